// Round 9
// baseline (416.303 us; speedup 1.0000x reference)
//
#include <hip/hip_runtime.h>

typedef __attribute__((ext_vector_type(8))) short short8;
typedef __attribute__((ext_vector_type(4))) short short4v;
typedef __attribute__((ext_vector_type(4))) float f32x4;
typedef unsigned short u16;
typedef unsigned int u32;

__device__ __forceinline__ float bf2f(u16 h) {
    return __uint_as_float(((u32)h) << 16);
}
__device__ __forceinline__ u16 f2bf(float f) {
    u32 u = __float_as_uint(f);
    u32 r = u + 0x7fffu + ((u >> 16) & 1u);   // RNE
    return (u16)(r >> 16);
}
// pack hi16(a), hi16(b) -> (b.hi<<16)|a.hi  (truncating bf16 pack, 1 instr)
__device__ __forceinline__ u32 pack_bf(float a, float b) {
    return __builtin_amdgcn_perm(__float_as_uint(b), __float_as_uint(a), 0x07060302u);
}

__device__ __forceinline__ void async_copy16(const void* g, void* l) {
    __builtin_amdgcn_global_load_lds(
        (const __attribute__((address_space(1))) void*)g,
        (__attribute__((address_space(3))) void*)l, 16, 0, 0);
}

// ---------------------------------------------------------------------------
// fp32 -> (bf16 hi, bf16 lo) split conversion. lo = bf16(v - f(hi)).
// ---------------------------------------------------------------------------
__global__ __launch_bounds__(256) void cvt_split(
    const float* __restrict__ in, u16* __restrict__ hi, u16* __restrict__ lo, int n4)
{
    int i = blockIdx.x * 256 + threadIdx.x;
    if (i >= n4) return;
    float4 v = ((const float4*)in)[i];
    short4v h, l;
    float vv[4] = {v.x, v.y, v.z, v.w};
#pragma unroll
    for (int j = 0; j < 4; j++) {
        u16 hb = f2bf(vv[j]);
        h[j] = (short)hb;
        l[j] = (short)f2bf(vv[j] - bf2f(hb));
    }
    ((short4v*)hi)[i] = h;
    ((short4v*)lo)[i] = l;
}

// 4 router weight matrices in one launch: 64 blocks per router.
__global__ __launch_bounds__(256) void cvt_split_w4(
    const float* __restrict__ w0, const float* __restrict__ w1,
    const float* __restrict__ w2, const float* __restrict__ w3,
    u16* __restrict__ hi, u16* __restrict__ lo)
{
    const int r = blockIdx.x >> 6;
    const float* src = (r == 0) ? w0 : (r == 1) ? w1 : (r == 2) ? w2 : w3;
    int i = (blockIdx.x & 63) * 256 + threadIdx.x;   // < 16384 float4s
    float4 v = ((const float4*)src)[i];
    short4v h, l;
    float vv[4] = {v.x, v.y, v.z, v.w};
#pragma unroll
    for (int j = 0; j < 4; j++) {
        u16 hb = f2bf(vv[j]);
        h[j] = (short)hb;
        l[j] = (short)f2bf(vv[j] - bf2f(hb));
    }
    ((short4v*)(hi + (long)r * 65536))[i] = h;
    ((short4v*)(lo + (long)r * 65536))[i] = l;
}

__global__ __launch_bounds__(256) void cvt_bf(
    const float* __restrict__ in, u16* __restrict__ out, int n4)
{
    int i = blockIdx.x * 256 + threadIdx.x;
    if (i >= n4) return;
    float4 v = ((const float4*)in)[i];
    short4v h;
    h[0] = (short)f2bf(v.x); h[1] = (short)f2bf(v.y);
    h[2] = (short)f2bf(v.z); h[3] = (short)f2bf(v.w);
    ((short4v*)out)[i] = h;
}

// ---------------------------------------------------------------------------
// bf16 GEMM: C[M][N] = cscale * (A[M][K] * B[N][K]^T). m97 structure.
// ---------------------------------------------------------------------------
template <typename CT>
__global__ __launch_bounds__(256) void gemm_bt(
    const u16* __restrict__ A, long lda, long bsA,
    const u16* __restrict__ Bm, long ldb, long bsB,
    CT* __restrict__ C, long ldc, long bsC, int K, float cscale)
{
    __shared__ __align__(16) u16 lsA[128 * 32];
    __shared__ __align__(16) u16 lsB[128 * 32];
    const int tid = threadIdx.x;
    const int wave = tid >> 6, lane = tid & 63;
    const int quad = lane >> 4, l15 = lane & 15;
    const int wm = wave >> 1, wn = wave & 1;
    const long m0 = (long)blockIdx.x * 128, n0 = (long)blockIdx.y * 128;
    A  += (long)blockIdx.z * bsA;
    Bm += (long)blockIdx.z * bsB;
    C  += (long)blockIdx.z * bsC;
    const int srow = lane >> 2, scol = (lane & 3) * 8;

    f32x4 acc[4][4];
#pragma unroll
    for (int i = 0; i < 4; i++)
#pragma unroll
        for (int j = 0; j < 4; j++) acc[i][j] = (f32x4){0.f, 0.f, 0.f, 0.f};

    const u16* ga0 = A + (m0 + (wave * 2 + 0) * 16 + srow) * lda + scol;
    const u16* ga1 = A + (m0 + (wave * 2 + 1) * 16 + srow) * lda + scol;
    const u16* gb0 = Bm + (n0 + (wave * 2 + 0) * 16 + srow) * ldb + scol;
    const u16* gb1 = Bm + (n0 + (wave * 2 + 1) * 16 + srow) * ldb + scol;
    u16* la0 = &lsA[(wave * 2 + 0) * 512];
    u16* la1 = &lsA[(wave * 2 + 1) * 512];
    u16* lb0 = &lsB[(wave * 2 + 0) * 512];
    u16* lb1 = &lsB[(wave * 2 + 1) * 512];

    for (int kk = 0; kk < K; kk += 32) {
        async_copy16(ga0 + kk, la0);
        async_copy16(ga1 + kk, la1);
        async_copy16(gb0 + kk, lb0);
        async_copy16(gb1 + kk, lb1);
        __syncthreads();
        short8 af[4], bf[4];
#pragma unroll
        for (int mt = 0; mt < 4; mt++)
            af[mt] = *(const short8*)&lsA[(wm * 64 + mt * 16 + l15) * 32 + quad * 8];
#pragma unroll
        for (int nt = 0; nt < 4; nt++)
            bf[nt] = *(const short8*)&lsB[(wn * 64 + nt * 16 + l15) * 32 + quad * 8];
#pragma unroll
        for (int mt = 0; mt < 4; mt++)
#pragma unroll
            for (int nt = 0; nt < 4; nt++)
                acc[mt][nt] = __builtin_amdgcn_mfma_f32_16x16x32_bf16(
                    af[mt], bf[nt], acc[mt][nt], 0, 0, 0);
        __syncthreads();
    }
#pragma unroll
    for (int mt = 0; mt < 4; mt++) {
        const long rowb = m0 + wm * 64 + mt * 16 + quad * 4;
#pragma unroll
        for (int nt = 0; nt < 4; nt++) {
            const long col = n0 + wn * 64 + nt * 16 + l15;
#pragma unroll
            for (int r = 0; r < 4; r++) {
                const float v = acc[mt][nt][r] * cscale;
                if constexpr (sizeof(CT) == 2)
                    C[(rowb + r) * ldc + col] = f2bf(v);
                else
                    C[(rowb + r) * ldc + col] = v;
            }
        }
    }
}

// ---------------------------------------------------------------------------
// Merged Q/K/V^T projection GEMMs. All three are M=1024, N=1024, K=256,
// lda=ldb=256, ldc=1024, bf16 out. z = sel*8 + batch; sel: 0=Q, 1=K, 2=V^T.
// ---------------------------------------------------------------------------
__global__ __launch_bounds__(256) void gemm_qkv(
    const u16* __restrict__ hbuf, const u16* __restrict__ eQT,
    const u16* __restrict__ eKT, const u16* __restrict__ eVT,
    u16* __restrict__ Qb, u16* __restrict__ Kb, u16* __restrict__ VTb)
{
    __shared__ __align__(16) u16 lsA[128 * 32];
    __shared__ __align__(16) u16 lsB[128 * 32];
    const int z = blockIdx.z;
    const int sel = z >> 3, bbz = z & 7;
    const long ab = (long)bbz * 262144;
    const u16* A  = ((sel == 2) ? eVT : hbuf) + ab;
    const u16* Bm = ((sel == 0) ? eQT : (sel == 1) ? eKT : hbuf) + ab;
    u16* C = ((sel == 0) ? Qb : (sel == 1) ? Kb : VTb) + (long)bbz * 1048576;
    const float cscale = (sel == 0) ? 0.180336880111f : 1.0f;

    const int tid = threadIdx.x;
    const int wave = tid >> 6, lane = tid & 63;
    const int quad = lane >> 4, l15 = lane & 15;
    const int wm = wave >> 1, wn = wave & 1;
    const long m0 = (long)blockIdx.x * 128, n0 = (long)blockIdx.y * 128;
    const int srow = lane >> 2, scol = (lane & 3) * 8;

    f32x4 acc[4][4];
#pragma unroll
    for (int i = 0; i < 4; i++)
#pragma unroll
        for (int j = 0; j < 4; j++) acc[i][j] = (f32x4){0.f, 0.f, 0.f, 0.f};

    const u16* ga0 = A + (m0 + (wave * 2 + 0) * 16 + srow) * 256 + scol;
    const u16* ga1 = A + (m0 + (wave * 2 + 1) * 16 + srow) * 256 + scol;
    const u16* gb0 = Bm + (n0 + (wave * 2 + 0) * 16 + srow) * 256 + scol;
    const u16* gb1 = Bm + (n0 + (wave * 2 + 1) * 16 + srow) * 256 + scol;
    u16* la0 = &lsA[(wave * 2 + 0) * 512];
    u16* la1 = &lsA[(wave * 2 + 1) * 512];
    u16* lb0 = &lsB[(wave * 2 + 0) * 512];
    u16* lb1 = &lsB[(wave * 2 + 1) * 512];

    for (int kk = 0; kk < 256; kk += 32) {
        async_copy16(ga0 + kk, la0);
        async_copy16(ga1 + kk, la1);
        async_copy16(gb0 + kk, lb0);
        async_copy16(gb1 + kk, lb1);
        __syncthreads();
        short8 af[4], bf[4];
#pragma unroll
        for (int mt = 0; mt < 4; mt++)
            af[mt] = *(const short8*)&lsA[(wm * 64 + mt * 16 + l15) * 32 + quad * 8];
#pragma unroll
        for (int nt = 0; nt < 4; nt++)
            bf[nt] = *(const short8*)&lsB[(wn * 64 + nt * 16 + l15) * 32 + quad * 8];
#pragma unroll
        for (int mt = 0; mt < 4; mt++)
#pragma unroll
            for (int nt = 0; nt < 4; nt++)
                acc[mt][nt] = __builtin_amdgcn_mfma_f32_16x16x32_bf16(
                    af[mt], bf[nt], acc[mt][nt], 0, 0, 0);
        __syncthreads();
    }
#pragma unroll
    for (int mt = 0; mt < 4; mt++) {
        const long rowb = m0 + wm * 64 + mt * 16 + quad * 4;
#pragma unroll
        for (int nt = 0; nt < 4; nt++) {
            const long col = n0 + wn * 64 + nt * 16 + l15;
#pragma unroll
            for (int r = 0; r < 4; r++)
                C[(rowb + r) * 1024 + col] = f2bf(acc[mt][nt][r] * cscale);
        }
    }
}

// ---------------------------------------------------------------------------
// Split-bf16 router logits, one precision segment per blockIdx.z:
// seg0 = Ah*Bh^T -> C0, seg1 = Al*Bh^T -> C1, seg2 = Ah*Bl^T -> C2.
// router_agg sums the three. 384 blocks (1.5/CU) vs 128 (0.5/CU) before.
// ---------------------------------------------------------------------------
__global__ __launch_bounds__(256) void gemm_router(
    const u16* __restrict__ Ah, const u16* __restrict__ Al,
    const u16* __restrict__ Bh, const u16* __restrict__ Bl,
    float* __restrict__ C0, float* __restrict__ C1, float* __restrict__ C2)
{
    __shared__ __align__(16) u16 lsA[128 * 32];
    __shared__ __align__(16) u16 lsB[128 * 32];
    const int seg = blockIdx.z;
    const u16* A = (seg == 1) ? Al : Ah;
    const u16* B = (seg == 2) ? Bl : Bh;
    float* C = (seg == 0) ? C0 : (seg == 1) ? C1 : C2;
    const int tid = threadIdx.x;
    const int wave = tid >> 6, lane = tid & 63;
    const int quad = lane >> 4, l15 = lane & 15;
    const int wm = wave >> 1, wn = wave & 1;
    const long m0 = (long)blockIdx.x * 128, n0 = (long)blockIdx.y * 128;
    const int srow = lane >> 2, scol = (lane & 3) * 8;
    const u16* ga = A + (m0 + (wave * 2) * 16 + srow) * 1024 + scol;
    const u16* gb = B + (n0 + (wave * 2) * 16 + srow) * 1024 + scol;
    u16* la0 = &lsA[(wave * 2 + 0) * 512];
    u16* la1 = &lsA[(wave * 2 + 1) * 512];
    u16* lb0 = &lsB[(wave * 2 + 0) * 512];
    u16* lb1 = &lsB[(wave * 2 + 1) * 512];

    f32x4 acc[4][4];
#pragma unroll
    for (int i = 0; i < 4; i++)
#pragma unroll
        for (int j = 0; j < 4; j++) acc[i][j] = (f32x4){0.f, 0.f, 0.f, 0.f};

    for (int kk = 0; kk < 1024; kk += 32) {
        async_copy16(ga + kk, la0);
        async_copy16(ga + 16384 + kk, la1);
        async_copy16(gb + kk, lb0);
        async_copy16(gb + 16384 + kk, lb1);
        __syncthreads();
        short8 af[4], bf[4];
#pragma unroll
        for (int mt = 0; mt < 4; mt++)
            af[mt] = *(const short8*)&lsA[(wm * 64 + mt * 16 + l15) * 32 + quad * 8];
#pragma unroll
        for (int nt = 0; nt < 4; nt++)
            bf[nt] = *(const short8*)&lsB[(wn * 64 + nt * 16 + l15) * 32 + quad * 8];
#pragma unroll
        for (int mt = 0; mt < 4; mt++)
#pragma unroll
            for (int nt = 0; nt < 4; nt++)
                acc[mt][nt] = __builtin_amdgcn_mfma_f32_16x16x32_bf16(
                    af[mt], bf[nt], acc[mt][nt], 0, 0, 0);
        __syncthreads();
    }
#pragma unroll
    for (int mt = 0; mt < 4; mt++) {
        const long rowb = m0 + wm * 64 + mt * 16 + quad * 4;
#pragma unroll
        for (int nt = 0; nt < 4; nt++) {
            const long col = n0 + wn * 64 + nt * 16 + l15;
#pragma unroll
            for (int r = 0; r < 4; r++)
                C[(rowb + r) * 256 + col] = acc[mt][nt][r];
        }
    }
}

// ---------------------------------------------------------------------------
// Per-token softmax over each router's 64 logits (= l0+l1+l2), scaled by
// importance, summed over tokens into w_raw[4][8][64] (fp32 atomics).
// ---------------------------------------------------------------------------
__global__ __launch_bounds__(128) void router_agg(
    const float* __restrict__ l0, const float* __restrict__ l1,
    const float* __restrict__ l2, const float* __restrict__ imp,
    float* __restrict__ w_raw)
{
    __shared__ float pref[32][257];
    const int tid = threadIdx.x;
    const int tl = tid >> 2, r = tid & 3;
    const int s = blockIdx.x * 32 + tl;
    const int b = s >> 10;
    const long off = (long)s * 256 + r * 64;
    float v[64];
#pragma unroll
    for (int i = 0; i < 16; i++) {
        float4 f0 = ((const float4*)(l0 + off))[i];
        float4 f1 = ((const float4*)(l1 + off))[i];
        float4 f2 = ((const float4*)(l2 + off))[i];
        v[i * 4 + 0] = f0.x + f1.x + f2.x;
        v[i * 4 + 1] = f0.y + f1.y + f2.y;
        v[i * 4 + 2] = f0.z + f1.z + f2.z;
        v[i * 4 + 3] = f0.w + f1.w + f2.w;
    }
    float mx = v[0];
#pragma unroll
    for (int i = 1; i < 64; i++) mx = fmaxf(mx, v[i]);
    float sum = 0.f;
#pragma unroll
    for (int i = 0; i < 64; i++) { v[i] = __expf(v[i] - mx); sum += v[i]; }
    const float scale = imp[s] / sum;
#pragma unroll
    for (int i = 0; i < 64; i++) pref[tl][r * 64 + i] = v[i] * scale;
    __syncthreads();
#pragma unroll
    for (int half = 0; half < 2; half++) {
        const int idx = tid + half * 128;
        const int r2 = idx >> 6, n = idx & 63;
        float acc = 0.f;
#pragma unroll 8
        for (int t = 0; t < 32; t++) acc += pref[t][r2 * 64 + n];
        atomicAdd(&w_raw[(r2 * 8 + b) * 64 + n], acc);
    }
}

// ---------------------------------------------------------------------------
// Normalize w, top-k (k=16 router 0, else 8), renormalize.
// ---------------------------------------------------------------------------
__global__ void topk_kernel(const float* __restrict__ w_raw,
                            float* __restrict__ topw, int* __restrict__ topi)
{
    const int r = blockIdx.x >> 3, b = blockIdx.x & 7;
    const int lane = threadIdx.x;
    const int k = (r == 0) ? 16 : 8;
    float w = w_raw[(r * 8 + b) * 64 + lane];
    float tot = w;
    for (int o2 = 32; o2 >= 1; o2 >>= 1) tot += __shfl_xor(tot, o2);
    w = w / (tot + 1e-8f);
    __shared__ float tw[16];
    __shared__ int ti[16];
    float cur = w;
    float ssum = 0.f;
    for (int j = 0; j < k; j++) {
        float m = cur; int mi = lane;
        for (int o2 = 32; o2 >= 1; o2 >>= 1) {
            float om = __shfl_xor(m, o2); int oi = __shfl_xor(mi, o2);
            if (om > m || (om == m && oi < mi)) { m = om; mi = oi; }
        }
        if (lane == 0) { tw[j] = m; ti[j] = mi; }
        ssum += m;
        if (lane == mi) cur = -1e30f;
    }
    __syncthreads();
    if (lane < 16) {
        topw[(r * 8 + b) * 16 + lane] = (lane < k) ? tw[lane] / (ssum + 1e-8f) : 0.f;
        topi[(r * 8 + b) * 16 + lane] = (lane < k) ? ti[lane] : 0;
    }
}

// ---------------------------------------------------------------------------
// out[b][j][i] = sum_k w[b,k] * pool[idx[b,k]][i][j]   (transposing gather-mix)
// ---------------------------------------------------------------------------
__global__ __launch_bounds__(256) void gather_mix(
    const float* __restrict__ pool, const float* __restrict__ topw,
    const int* __restrict__ topi, u16* __restrict__ out,
    int I, int J, int k)
{
    __shared__ float tile[64][65];
    const int b = blockIdx.z;
    const long IJ = (long)I * J;
    const int i0 = blockIdx.x * 64, j0 = blockIdx.y * 64;
    const float* tw = topw + b * 16;
    const int* ti = topi + b * 16;
    const int tid = threadIdx.x;
    const int il = tid >> 2, jg = tid & 3;
    float acc[16];
#pragma unroll
    for (int m = 0; m < 16; m++) acc[m] = 0.f;
    for (int kk = 0; kk < k; kk++) {
        const float wgt = tw[kk];
        const long n = ti[kk];
        const float* src = pool + n * IJ + (long)(i0 + il) * J + j0 + jg * 16;
        float4 a0 = ((const float4*)src)[0];
        float4 a1 = ((const float4*)src)[1];
        float4 a2 = ((const float4*)src)[2];
        float4 a3 = ((const float4*)src)[3];
        acc[0] += wgt * a0.x;  acc[1] += wgt * a0.y;
        acc[2] += wgt * a0.z;  acc[3] += wgt * a0.w;
        acc[4] += wgt * a1.x;  acc[5] += wgt * a1.y;
        acc[6] += wgt * a1.z;  acc[7] += wgt * a1.w;
        acc[8] += wgt * a2.x;  acc[9] += wgt * a2.y;
        acc[10] += wgt * a2.z; acc[11] += wgt * a2.w;
        acc[12] += wgt * a3.x; acc[13] += wgt * a3.y;
        acc[14] += wgt * a3.z; acc[15] += wgt * a3.w;
    }
#pragma unroll
    for (int m = 0; m < 16; m++) tile[il][jg * 16 + m] = acc[m];
    __syncthreads();
    const int jl = tid >> 2, ig = tid & 3;
    short8 o0, o1;
#pragma unroll
    for (int m = 0; m < 8; m++) {
        o0[m] = (short)f2bf(tile[ig * 16 + m][jl]);
        o1[m] = (short)f2bf(tile[ig * 16 + 8 + m][jl]);
    }
    u16* dst = out + (long)b * IJ + (long)(j0 + jl) * I + i0 + ig * 16;
    *(short8*)dst = o0;
    *(short8*)(dst + 8) = o1;
}

// ---------------------------------------------------------------------------
// Merged eQ/eK/eV gather-mix (same pool, I=256, J=1024, k=8).
// z = r*8 + b; r selects router slice (1..3) and output.
// ---------------------------------------------------------------------------
__global__ __launch_bounds__(256) void gather_mix3(
    const float* __restrict__ pool, const float* __restrict__ topw,
    const int* __restrict__ topi, u16* __restrict__ eQT,
    u16* __restrict__ eKT, u16* __restrict__ eVT)
{
    __shared__ float tile[64][65];
    const int z = blockIdx.z;
    const int r = z >> 3, b = z & 7;
    u16* out = (r == 0) ? eQT : (r == 1) ? eKT : eVT;
    const long IJ = 262144;   // 256*1024
    const int i0 = blockIdx.x * 64, j0 = blockIdx.y * 64;
    const float* tw = topw + (1 + r) * 128 + b * 16;
    const int* ti = topi + (1 + r) * 128 + b * 16;
    const int tid = threadIdx.x;
    const int il = tid >> 2, jg = tid & 3;
    float acc[16];
#pragma unroll
    for (int m = 0; m < 16; m++) acc[m] = 0.f;
    for (int kk = 0; kk < 8; kk++) {
        const float wgt = tw[kk];
        const long n = ti[kk];
        const float* src = pool + n * IJ + (long)(i0 + il) * 1024 + j0 + jg * 16;
        float4 a0 = ((const float4*)src)[0];
        float4 a1 = ((const float4*)src)[1];
        float4 a2 = ((const float4*)src)[2];
        float4 a3 = ((const float4*)src)[3];
        acc[0] += wgt * a0.x;  acc[1] += wgt * a0.y;
        acc[2] += wgt * a0.z;  acc[3] += wgt * a0.w;
        acc[4] += wgt * a1.x;  acc[5] += wgt * a1.y;
        acc[6] += wgt * a1.z;  acc[7] += wgt * a1.w;
        acc[8] += wgt * a2.x;  acc[9] += wgt * a2.y;
        acc[10] += wgt * a2.z; acc[11] += wgt * a2.w;
        acc[12] += wgt * a3.x; acc[13] += wgt * a3.y;
        acc[14] += wgt * a3.z; acc[15] += wgt * a3.w;
    }
#pragma unroll
    for (int m = 0; m < 16; m++) tile[il][jg * 16 + m] = acc[m];
    __syncthreads();
    const int jl = tid >> 2, ig = tid & 3;
    short8 o0, o1;
#pragma unroll
    for (int m = 0; m < 8; m++) {
        o0[m] = (short)f2bf(tile[ig * 16 + m][jl]);
        o1[m] = (short)f2bf(tile[ig * 16 + 8 + m][jl]);
    }
    u16* dst = out + (long)b * IJ + (long)(j0 + jl) * 256 + i0 + ig * 16;
    *(short8*)dst = o0;
    *(short8*)(dst + 8) = o1;
}

// ---------------------------------------------------------------------------
// Causal flash attention, S^T formulation (R0 structure — best measured).
// Q (pre-scaled by 1/8*log2e), K: [B][S][D] bf16; VT: [B][D][S] bf16.
// One wave = q-tiles {pr, 31-pr} of one (b,h) -> exactly 17 64-key iterations.
// R8 additions (zero register-structure change):
//  - XCD swizzle: logical block bidx = (p&7)*64 + (p>>3). The 4 blocks
//    sharing one (b,h)'s K/V land on ONE XCD's L2 instead of 4 (dispatch
//    round-robins p%8) -> FETCH was 2.5x the 32MB K/V footprint; unprefetched
//    V loads now come from warm L2 (~200cy) not HBM (~900cy).
//  - s_setprio(1) around QK and PV MFMA clusters (T5: +4-7% for
//    independent non-barrier waves at different phases, which these are).
// ---------------------------------------------------------------------------
__global__ __launch_bounds__(256, 2) void flash_attn(
    const u16* __restrict__ Qg, const u16* __restrict__ Kg,
    const u16* __restrict__ Vt, u16* __restrict__ Og)
{
    __shared__ __align__(16) u16 plds[4][32 * 72];   // per-wave P, stride 72 u16
    const int tid = threadIdx.x;
    const int wv = tid >> 6, lane = tid & 63;
    const int quad = lane >> 4, l15 = lane & 15;
    const int p = blockIdx.x;                    // physical block 0..511
    const int bidx = (p & 7) * 64 + (p >> 3);    // XCD-contiguous logical block
    const int gw = bidx * 4 + wv;
    const int pr = gw & 15;
    const int bh = gw >> 4;                  // 0..127, same for all waves in block
    const int hh = bh & 15, bb = bh >> 4;
    const long SD = 1024L * 1024L;
    const u16* Qb = Qg + (long)bb * SD + hh * 64;
    const u16* Kb = Kg + (long)bb * SD + hh * 64;
    const u16* Vb = Vt + (long)bb * SD + (long)hh * 64 * 1024;
    u16* myp = plds[wv];

    for (int half = 0; half < 2; half++) {
        const int qt = half ? (31 - pr) : pr;
        const int q0 = qt * 32;

        short8 qf[2][2];
#pragma unroll
        for (int mt = 0; mt < 2; mt++)
#pragma unroll
            for (int kb = 0; kb < 2; kb++)
                qf[mt][kb] = *(const short8*)(Qb + (long)(q0 + mt * 16 + l15) * 1024 + kb * 32 + quad * 8);

        f32x4 o[2][4];
        float mrow[2] = {-3e38f, -3e38f}, lrow[2] = {0.f, 0.f};
#pragma unroll
        for (int mt = 0; mt < 2; mt++)
#pragma unroll
            for (int nt = 0; nt < 4; nt++) o[mt][nt] = (f32x4){0.f, 0.f, 0.f, 0.f};

        const int ntile = (q0 + 95) >> 6;    // ceil((q0+32)/64)
        short8 kf[4][2], kn[4][2];
#pragma unroll
        for (int kt = 0; kt < 4; kt++)
#pragma unroll
            for (int kb = 0; kb < 2; kb++)
                kf[kt][kb] = *(const short8*)(Kb + (long)(kt * 16 + l15) * 1024 + kb * 32 + quad * 8);

        for (int it = 0; it < ntile; it++) {
            const int k2 = it * 64;
            const bool last = (it == ntile - 1);
            // S^T[key][q] = K·Q^T
            f32x4 st[4][2];
            __builtin_amdgcn_s_setprio(1);
#pragma unroll
            for (int kt = 0; kt < 4; kt++)
#pragma unroll
                for (int q_ = 0; q_ < 2; q_++) {
                    f32x4 z = (f32x4){0.f, 0.f, 0.f, 0.f};
                    z = __builtin_amdgcn_mfma_f32_16x16x32_bf16(kf[kt][0], qf[q_][0], z, 0, 0, 0);
                    z = __builtin_amdgcn_mfma_f32_16x16x32_bf16(kf[kt][1], qf[q_][1], z, 0, 0, 0);
                    st[kt][q_] = z;
                }
            __builtin_amdgcn_s_setprio(0);
            // V loads for this iter (latency hidden under softmax)
            short8 vf[4][2];
#pragma unroll
            for (int nt = 0; nt < 4; nt++)
#pragma unroll
                for (int kh = 0; kh < 2; kh++)
                    vf[nt][kh] = *(const short8*)(Vb + (long)(nt * 16 + l15) * 1024 + k2 + kh * 32 + quad * 8);
            // prefetch next K tile
            if (it + 1 < ntile) {
#pragma unroll
                for (int kt = 0; kt < 4; kt++)
#pragma unroll
                    for (int kb = 0; kb < 2; kb++)
                        kn[kt][kb] = *(const short8*)(Kb + (long)(k2 + 64 + kt * 16 + l15) * 1024 + kb * 32 + quad * 8);
            }
            // online softmax per q-column (lane&15 holds q)
            float am[2];
#pragma unroll
            for (int q_ = 0; q_ < 2; q_++) {
                if (last) {
#pragma unroll
                    for (int kt = 0; kt < 4; kt++)
#pragma unroll
                        for (int r = 0; r < 4; r++)
                            if (k2 + kt * 16 + quad * 4 + r > q0 + q_ * 16 + l15)
                                st[kt][q_][r] = -3e38f;
                }
                // balanced max tree (exact)
                float t0 = fmaxf(fmaxf(st[0][q_][0], st[0][q_][1]), fmaxf(st[0][q_][2], st[0][q_][3]));
                float t1 = fmaxf(fmaxf(st[1][q_][0], st[1][q_][1]), fmaxf(st[1][q_][2], st[1][q_][3]));
                float t2 = fmaxf(fmaxf(st[2][q_][0], st[2][q_][1]), fmaxf(st[2][q_][2], st[2][q_][3]));
                float t3 = fmaxf(fmaxf(st[3][q_][0], st[3][q_][1]), fmaxf(st[3][q_][2], st[3][q_][3]));
                float cm = fmaxf(fmaxf(t0, t1), fmaxf(t2, t3));
                cm = fmaxf(cm, __shfl_xor(cm, 16));
                cm = fmaxf(cm, __shfl_xor(cm, 32));
                const float mn = fmaxf(mrow[q_], cm);
                am[q_] = exp2f(mrow[q_] - mn);
                mrow[q_] = mn;
                // fold +log2(1+2^-9) so the truncating bf16 pack is ~unbiased
                const float moff = 0.00281502f - mn;
                float s4[4];
#pragma unroll
                for (int kt = 0; kt < 4; kt++) {
                    float p0 = exp2f(st[kt][q_][0] + moff);
                    float p1 = exp2f(st[kt][q_][1] + moff);
                    float p2 = exp2f(st[kt][q_][2] + moff);
                    float p3 = exp2f(st[kt][q_][3] + moff);
                    s4[kt] = (p0 + p1) + (p2 + p3);
                    u32 w0 = pack_bf(p0, p1);
                    u32 w1 = pack_bf(p2, p3);
                    *(uint2*)&myp[(q_ * 16 + l15) * 72 + kt * 16 + quad * 4] = make_uint2(w0, w1);
                }
                float rs = (s4[0] + s4[1]) + (s4[2] + s4[3]);
                rs += __shfl_xor(rs, 16);
                rs += __shfl_xor(rs, 32);
                lrow[q_] = lrow[q_] * am[q_] + rs;
            }
            // redistribute alpha from q-on-l15 to q-on-row layout
            float av[2][4];
#pragma unroll
            for (int mt = 0; mt < 2; mt++)
#pragma unroll
                for (int r = 0; r < 4; r++)
                    av[mt][r] = __shfl(am[mt], quad * 4 + r);
            asm volatile("s_waitcnt lgkmcnt(0)" ::: "memory");
            short8 pf0[2], pf1[2];
#pragma unroll
            for (int kh = 0; kh < 2; kh++) {
                pf0[kh] = *(const short8*)&myp[(l15) * 72 + kh * 32 + quad * 8];
                pf1[kh] = *(const short8*)&myp[(16 + l15) * 72 + kh * 32 + quad * 8];
            }
#pragma unroll
            for (int mt = 0; mt < 2; mt++)
#pragma unroll
                for (int nt = 0; nt < 4; nt++)
#pragma unroll
                    for (int r = 0; r < 4; r++) o[mt][nt][r] *= av[mt][r];
            __builtin_amdgcn_s_setprio(1);
#pragma unroll
            for (int nt = 0; nt < 4; nt++)
#pragma unroll
                for (int kh = 0; kh < 2; kh++) {
                    o[0][nt] = __builtin_amdgcn_mfma_f32_16x16x32_bf16(pf0[kh], vf[nt][kh], o[0][nt], 0, 0, 0);
                    o[1][nt] = __builtin_amdgcn_mfma_f32_16x16x32_bf16(pf1[kh], vf[nt][kh], o[1][nt], 0, 0, 0);
                }
            __builtin_amdgcn_s_setprio(0);
            if (it + 1 < ntile) {
#pragma unroll
                for (int kt = 0; kt < 4; kt++)
#pragma unroll
                    for (int kb = 0; kb < 2; kb++) kf[kt][kb] = kn[kt][kb];
            }
        }
        // epilogue
#pragma unroll
        for (int mt = 0; mt < 2; mt++)
#pragma unroll
            for (int r = 0; r < 4; r++) {
                const float li = 1.0f / __shfl(lrow[mt], quad * 4 + r);
                const long row = q0 + mt * 16 + quad * 4 + r;
#pragma unroll
                for (int nt = 0; nt < 4; nt++)
                    Og[(long)bb * SD + row * 1024 + hh * 64 + nt * 16 + l15] =
                        f2bf(o[mt][nt][r] * li);
            }
    }
}

// ---------------------------------------------------------------------------
extern "C" void kernel_launch(void* const* d_in, const int* in_sizes, int n_in,
                              void* d_out, int out_size, void* d_ws, size_t ws_size,
                              hipStream_t stream)
{
    const float* x   = (const float*)d_in[0];
    const float* imp = (const float*)d_in[1];
    const float* cn  = (const float*)d_in[6];
    const float* ep  = (const float*)d_in[7];
    const float* Wo  = (const float*)d_in[8];
    float* outp = (float*)d_out;
    char* ws = (char*)d_ws;

    // d_out (33.55 MB) doubles as scratch for x_hi/x_lo until the final GEMM.
    u16* xh = (u16*)d_out;                    // [8192][1024] bf16
    u16* xl = xh + 8388608;                   // [8192][1024] bf16

    u16*   Wh     = (u16*)(ws + 0);           // [256][1024] bf16
    u16*   Wl     = (u16*)(ws + 524288);      // [256][1024] bf16
    u16*   Wobf   = (u16*)(ws + 1048576);     // [1024][1024] bf16
    float* w_raw  = (float*)(ws + 3145728);   // [4][8][64]
    float* topw   = (float*)(ws + 3153920);   // [4][8][16]
    int*   topi   = (int*)(ws + 3155968);     // [4][8][16]
    // logits seg buffers: L0 in the pre-Kb region; L1/L2 park in the Qb
    // region (both dead before gemm_qkv writes Qb).
    float* logit0 = (float*)(ws + 4194304);   // [8192][256] fp32
    float* logit1 = (float*)(ws + 33554432);  // [8192][256] fp32 (Qb region)
    float* logit2 = (float*)(ws + 41943040);  // [8192][256] fp32 (Qb region)
    u16*   scT    = (u16*)(ws + 12582912);    // [8][256][1024] (dead after h GEMM)
    u16*   eQT    = (u16*)(ws + 16777216);    // [8][1024][256] (dead after QKV GEMM)
    u16*   Kb     = (u16*)(ws + 4194304);     // [8][1024][1024] (written after logits die)
    u16*   hbuf   = (u16*)(ws + 20971520);    // [8][1024][256]
    u16*   eKT    = (u16*)(ws + 25165824);    // [8][1024][256]
    u16*   eVT    = (u16*)(ws + 29360128);    // [8][1024][256]
    u16*   Qb     = (u16*)(ws + 33554432);    // [8][1024][1024]
    u16*   VTb    = (u16*)(ws + 50331648);    // [8][1024(D)][1024(S)]
    u16*   aout   = (u16*)(ws + 67108864);    // [8][1024][1024]

    // 0) precision splits / conversions
    cvt_split<<<dim3(8192), 256, 0, stream>>>(x, xh, xl, 2097152);
    cvt_split_w4<<<dim3(256), 256, 0, stream>>>(
        (const float*)d_in[2], (const float*)d_in[3],
        (const float*)d_in[4], (const float*)d_in[5], Wh, Wl);
    cvt_bf<<<dim3(1024), 256, 0, stream>>>(Wo, Wobf, 262144);
    hipMemsetAsync(w_raw, 0, 4 * 8 * 64 * 4, stream);

    // 1) router logits, split-bf16, one segment per z (384 blocks)
    gemm_router<<<dim3(64, 2, 3), 256, 0, stream>>>(
        xh, xl, Wh, Wl, logit0, logit1, logit2);
    // 2) softmax + importance aggregation, 3) top-k (all fp32)
    router_agg<<<dim3(256), 128, 0, stream>>>(logit0, logit1, logit2, imp, w_raw);
    topk_kernel<<<dim3(32), 64, 0, stream>>>(w_raw, topw, topi);
    // 4) gathered expert mixes (fp32 pools -> bf16, stored transposed/K-contig)
    gather_mix<<<dim3(16, 4, 8), 256, 0, stream>>>(cn, topw + 0 * 128, topi + 0 * 128, scT, 1024, 256, 16);
    gather_mix3<<<dim3(4, 16, 24), 256, 0, stream>>>(ep, topw, topi, eQT, eKT, eVT);
    // 5) h[b] = x[b] @ scT[b]^T   (M=1024,N=256,K=1024)
    gemm_bt<u16><<<dim3(8, 2, 8), 256, 0, stream>>>(
        xh, 1024, 1048576, scT, 1024, 262144, hbuf, 256, 262144, 1024, 1.0f);
    // 6) Q/K/V^T in one launch (1536 blocks = 6/CU).
    gemm_qkv<<<dim3(8, 8, 24), 256, 0, stream>>>(hbuf, eQT, eKT, eVT, Qb, Kb, VTb);
    // 7) causal flash attention (512 blocks, XCD-grouped (b,h) sharing)
    flash_attn<<<dim3(512), 256, 0, stream>>>(Qb, Kb, VTb, aout);
    // 8) output projection: out = aout @ W_O^T (fp32 out, overwrites xh/xl scratch)
    gemm_bt<float><<<dim3(64, 8, 1), 256, 0, stream>>>(
        aout, 1024, 0, Wobf, 1024, 0, outp, 1024, 0, 1024, 1.0f);
}

// Round 10
// 404.232 us; speedup vs baseline: 1.0299x; 1.0299x over previous
//
#include <hip/hip_runtime.h>

typedef __attribute__((ext_vector_type(8))) short short8;
typedef __attribute__((ext_vector_type(4))) short short4v;
typedef __attribute__((ext_vector_type(4))) float f32x4;
typedef unsigned short u16;
typedef unsigned int u32;

__device__ __forceinline__ float bf2f(u16 h) {
    return __uint_as_float(((u32)h) << 16);
}
__device__ __forceinline__ u16 f2bf(float f) {
    u32 u = __float_as_uint(f);
    u32 r = u + 0x7fffu + ((u >> 16) & 1u);   // RNE
    return (u16)(r >> 16);
}
// pack hi16(a), hi16(b) -> (b.hi<<16)|a.hi  (truncating bf16 pack, 1 instr)
__device__ __forceinline__ u32 pack_bf(float a, float b) {
    return __builtin_amdgcn_perm(__float_as_uint(b), __float_as_uint(a), 0x07060302u);
}

__device__ __forceinline__ void async_copy16(const void* g, void* l) {
    __builtin_amdgcn_global_load_lds(
        (const __attribute__((address_space(1))) void*)g,
        (__attribute__((address_space(3))) void*)l, 16, 0, 0);
}

// ---------------------------------------------------------------------------
// fp32 -> (bf16 hi, bf16 lo) split conversion. lo = bf16(v - f(hi)).
// ---------------------------------------------------------------------------
__global__ __launch_bounds__(256) void cvt_split(
    const float* __restrict__ in, u16* __restrict__ hi, u16* __restrict__ lo, int n4)
{
    int i = blockIdx.x * 256 + threadIdx.x;
    if (i >= n4) return;
    float4 v = ((const float4*)in)[i];
    short4v h, l;
    float vv[4] = {v.x, v.y, v.z, v.w};
#pragma unroll
    for (int j = 0; j < 4; j++) {
        u16 hb = f2bf(vv[j]);
        h[j] = (short)hb;
        l[j] = (short)f2bf(vv[j] - bf2f(hb));
    }
    ((short4v*)hi)[i] = h;
    ((short4v*)lo)[i] = l;
}

// 4 router weight matrices in one launch: 64 blocks per router.
__global__ __launch_bounds__(256) void cvt_split_w4(
    const float* __restrict__ w0, const float* __restrict__ w1,
    const float* __restrict__ w2, const float* __restrict__ w3,
    u16* __restrict__ hi, u16* __restrict__ lo)
{
    const int r = blockIdx.x >> 6;
    const float* src = (r == 0) ? w0 : (r == 1) ? w1 : (r == 2) ? w2 : w3;
    int i = (blockIdx.x & 63) * 256 + threadIdx.x;   // < 16384 float4s
    float4 v = ((const float4*)src)[i];
    short4v h, l;
    float vv[4] = {v.x, v.y, v.z, v.w};
#pragma unroll
    for (int j = 0; j < 4; j++) {
        u16 hb = f2bf(vv[j]);
        h[j] = (short)hb;
        l[j] = (short)f2bf(vv[j] - bf2f(hb));
    }
    ((short4v*)(hi + (long)r * 65536))[i] = h;
    ((short4v*)(lo + (long)r * 65536))[i] = l;
}

__global__ __launch_bounds__(256) void cvt_bf(
    const float* __restrict__ in, u16* __restrict__ out, int n4)
{
    int i = blockIdx.x * 256 + threadIdx.x;
    if (i >= n4) return;
    float4 v = ((const float4*)in)[i];
    short4v h;
    h[0] = (short)f2bf(v.x); h[1] = (short)f2bf(v.y);
    h[2] = (short)f2bf(v.z); h[3] = (short)f2bf(v.w);
    ((short4v*)out)[i] = h;
}

// ---------------------------------------------------------------------------
// bf16 GEMM: C[M][N] = cscale * (A[M][K] * B[N][K]^T). m97 structure,
// BK=64: one barrier pair per 64 K-elements (was 32) — halves the
// __syncthreads + vmcnt-drain count, the known stall of this structure.
// LDS layout per 16-row block: [k-chunk(2)][row(16)][32 u16] (each
// async_copy16 wave fills one contiguous [16][32] chunk). MFMA order is
// identical to BK=32 (kb=0 then kb=1) -> bitwise-same accumulation.
// K must be a multiple of 64 (all call sites: 1024/256/1024/1024).
// ---------------------------------------------------------------------------
template <typename CT>
__global__ __launch_bounds__(256) void gemm_bt(
    const u16* __restrict__ A, long lda, long bsA,
    const u16* __restrict__ Bm, long ldb, long bsB,
    CT* __restrict__ C, long ldc, long bsC, int K, float cscale)
{
    __shared__ __align__(16) u16 lsA[128 * 64];
    __shared__ __align__(16) u16 lsB[128 * 64];
    const int tid = threadIdx.x;
    const int wave = tid >> 6, lane = tid & 63;
    const int quad = lane >> 4, l15 = lane & 15;
    const int wm = wave >> 1, wn = wave & 1;
    const long m0 = (long)blockIdx.x * 128, n0 = (long)blockIdx.y * 128;
    A  += (long)blockIdx.z * bsA;
    Bm += (long)blockIdx.z * bsB;
    C  += (long)blockIdx.z * bsC;
    const int srow = lane >> 2, scol = (lane & 3) * 8;

    f32x4 acc[4][4];
#pragma unroll
    for (int i = 0; i < 4; i++)
#pragma unroll
        for (int j = 0; j < 4; j++) acc[i][j] = (f32x4){0.f, 0.f, 0.f, 0.f};

    const u16* ga0 = A + (m0 + (wave * 2 + 0) * 16 + srow) * lda + scol;
    const u16* ga1 = A + (m0 + (wave * 2 + 1) * 16 + srow) * lda + scol;
    const u16* gb0 = Bm + (n0 + (wave * 2 + 0) * 16 + srow) * ldb + scol;
    const u16* gb1 = Bm + (n0 + (wave * 2 + 1) * 16 + srow) * ldb + scol;
    u16* laA = &lsA[(wave * 2 + 0) * 1024];
    u16* laB = &lsA[(wave * 2 + 1) * 1024];
    u16* lbA = &lsB[(wave * 2 + 0) * 1024];
    u16* lbB = &lsB[(wave * 2 + 1) * 1024];

    for (int kk = 0; kk < K; kk += 64) {
        async_copy16(ga0 + kk,      laA);
        async_copy16(ga0 + kk + 32, laA + 512);
        async_copy16(ga1 + kk,      laB);
        async_copy16(ga1 + kk + 32, laB + 512);
        async_copy16(gb0 + kk,      lbA);
        async_copy16(gb0 + kk + 32, lbA + 512);
        async_copy16(gb1 + kk,      lbB);
        async_copy16(gb1 + kk + 32, lbB + 512);
        __syncthreads();
#pragma unroll
        for (int kb = 0; kb < 2; kb++) {
            short8 af[4], bf[4];
#pragma unroll
            for (int mt = 0; mt < 4; mt++)
                af[mt] = *(const short8*)&lsA[(wm * 4 + mt) * 1024 + kb * 512 + l15 * 32 + quad * 8];
#pragma unroll
            for (int nt = 0; nt < 4; nt++)
                bf[nt] = *(const short8*)&lsB[(wn * 4 + nt) * 1024 + kb * 512 + l15 * 32 + quad * 8];
#pragma unroll
            for (int mt = 0; mt < 4; mt++)
#pragma unroll
                for (int nt = 0; nt < 4; nt++)
                    acc[mt][nt] = __builtin_amdgcn_mfma_f32_16x16x32_bf16(
                        af[mt], bf[nt], acc[mt][nt], 0, 0, 0);
        }
        __syncthreads();
    }
#pragma unroll
    for (int mt = 0; mt < 4; mt++) {
        const long rowb = m0 + wm * 64 + mt * 16 + quad * 4;
#pragma unroll
        for (int nt = 0; nt < 4; nt++) {
            const long col = n0 + wn * 64 + nt * 16 + l15;
#pragma unroll
            for (int r = 0; r < 4; r++) {
                const float v = acc[mt][nt][r] * cscale;
                if constexpr (sizeof(CT) == 2)
                    C[(rowb + r) * ldc + col] = f2bf(v);
                else
                    C[(rowb + r) * ldc + col] = v;
            }
        }
    }
}

// ---------------------------------------------------------------------------
// Merged Q/K/V^T projection GEMMs, BK=64. All three are M=1024, N=1024,
// K=256 (4 K-steps), lda=ldb=256, ldc=1024, bf16 out. z = sel*8 + batch.
// ---------------------------------------------------------------------------
__global__ __launch_bounds__(256) void gemm_qkv(
    const u16* __restrict__ hbuf, const u16* __restrict__ eQT,
    const u16* __restrict__ eKT, const u16* __restrict__ eVT,
    u16* __restrict__ Qb, u16* __restrict__ Kb, u16* __restrict__ VTb)
{
    __shared__ __align__(16) u16 lsA[128 * 64];
    __shared__ __align__(16) u16 lsB[128 * 64];
    const int z = blockIdx.z;
    const int sel = z >> 3, bbz = z & 7;
    const long ab = (long)bbz * 262144;
    const u16* A  = ((sel == 2) ? eVT : hbuf) + ab;
    const u16* Bm = ((sel == 0) ? eQT : (sel == 1) ? eKT : hbuf) + ab;
    u16* C = ((sel == 0) ? Qb : (sel == 1) ? Kb : VTb) + (long)bbz * 1048576;
    const float cscale = (sel == 0) ? 0.180336880111f : 1.0f;

    const int tid = threadIdx.x;
    const int wave = tid >> 6, lane = tid & 63;
    const int quad = lane >> 4, l15 = lane & 15;
    const int wm = wave >> 1, wn = wave & 1;
    const long m0 = (long)blockIdx.x * 128, n0 = (long)blockIdx.y * 128;
    const int srow = lane >> 2, scol = (lane & 3) * 8;

    f32x4 acc[4][4];
#pragma unroll
    for (int i = 0; i < 4; i++)
#pragma unroll
        for (int j = 0; j < 4; j++) acc[i][j] = (f32x4){0.f, 0.f, 0.f, 0.f};

    const u16* ga0 = A + (m0 + (wave * 2 + 0) * 16 + srow) * 256 + scol;
    const u16* ga1 = A + (m0 + (wave * 2 + 1) * 16 + srow) * 256 + scol;
    const u16* gb0 = Bm + (n0 + (wave * 2 + 0) * 16 + srow) * 256 + scol;
    const u16* gb1 = Bm + (n0 + (wave * 2 + 1) * 16 + srow) * 256 + scol;
    u16* laA = &lsA[(wave * 2 + 0) * 1024];
    u16* laB = &lsA[(wave * 2 + 1) * 1024];
    u16* lbA = &lsB[(wave * 2 + 0) * 1024];
    u16* lbB = &lsB[(wave * 2 + 1) * 1024];

    for (int kk = 0; kk < 256; kk += 64) {
        async_copy16(ga0 + kk,      laA);
        async_copy16(ga0 + kk + 32, laA + 512);
        async_copy16(ga1 + kk,      laB);
        async_copy16(ga1 + kk + 32, laB + 512);
        async_copy16(gb0 + kk,      lbA);
        async_copy16(gb0 + kk + 32, lbA + 512);
        async_copy16(gb1 + kk,      lbB);
        async_copy16(gb1 + kk + 32, lbB + 512);
        __syncthreads();
#pragma unroll
        for (int kb = 0; kb < 2; kb++) {
            short8 af[4], bf[4];
#pragma unroll
            for (int mt = 0; mt < 4; mt++)
                af[mt] = *(const short8*)&lsA[(wm * 4 + mt) * 1024 + kb * 512 + l15 * 32 + quad * 8];
#pragma unroll
            for (int nt = 0; nt < 4; nt++)
                bf[nt] = *(const short8*)&lsB[(wn * 4 + nt) * 1024 + kb * 512 + l15 * 32 + quad * 8];
#pragma unroll
            for (int mt = 0; mt < 4; mt++)
#pragma unroll
                for (int nt = 0; nt < 4; nt++)
                    acc[mt][nt] = __builtin_amdgcn_mfma_f32_16x16x32_bf16(
                        af[mt], bf[nt], acc[mt][nt], 0, 0, 0);
        }
        __syncthreads();
    }
#pragma unroll
    for (int mt = 0; mt < 4; mt++) {
        const long rowb = m0 + wm * 64 + mt * 16 + quad * 4;
#pragma unroll
        for (int nt = 0; nt < 4; nt++) {
            const long col = n0 + wn * 64 + nt * 16 + l15;
#pragma unroll
            for (int r = 0; r < 4; r++)
                C[(rowb + r) * 1024 + col] = f2bf(acc[mt][nt][r] * cscale);
        }
    }
}

// ---------------------------------------------------------------------------
// Split-bf16 router logits, BK=64, one precision segment per blockIdx.z:
// seg0 = Ah*Bh^T -> C0, seg1 = Al*Bh^T -> C1, seg2 = Ah*Bl^T -> C2.
// router_agg sums the three. 384 blocks (1.5/CU).
// ---------------------------------------------------------------------------
__global__ __launch_bounds__(256) void gemm_router(
    const u16* __restrict__ Ah, const u16* __restrict__ Al,
    const u16* __restrict__ Bh, const u16* __restrict__ Bl,
    float* __restrict__ C0, float* __restrict__ C1, float* __restrict__ C2)
{
    __shared__ __align__(16) u16 lsA[128 * 64];
    __shared__ __align__(16) u16 lsB[128 * 64];
    const int seg = blockIdx.z;
    const u16* A = (seg == 1) ? Al : Ah;
    const u16* B = (seg == 2) ? Bl : Bh;
    float* C = (seg == 0) ? C0 : (seg == 1) ? C1 : C2;
    const int tid = threadIdx.x;
    const int wave = tid >> 6, lane = tid & 63;
    const int quad = lane >> 4, l15 = lane & 15;
    const int wm = wave >> 1, wn = wave & 1;
    const long m0 = (long)blockIdx.x * 128, n0 = (long)blockIdx.y * 128;
    const int srow = lane >> 2, scol = (lane & 3) * 8;
    const u16* ga = A + (m0 + (wave * 2) * 16 + srow) * 1024 + scol;
    const u16* gb = B + (n0 + (wave * 2) * 16 + srow) * 1024 + scol;
    u16* laA = &lsA[(wave * 2 + 0) * 1024];
    u16* laB = &lsA[(wave * 2 + 1) * 1024];
    u16* lbA = &lsB[(wave * 2 + 0) * 1024];
    u16* lbB = &lsB[(wave * 2 + 1) * 1024];

    f32x4 acc[4][4];
#pragma unroll
    for (int i = 0; i < 4; i++)
#pragma unroll
        for (int j = 0; j < 4; j++) acc[i][j] = (f32x4){0.f, 0.f, 0.f, 0.f};

    for (int kk = 0; kk < 1024; kk += 64) {
        async_copy16(ga + kk,              laA);
        async_copy16(ga + kk + 32,         laA + 512);
        async_copy16(ga + 16384 + kk,      laB);
        async_copy16(ga + 16384 + kk + 32, laB + 512);
        async_copy16(gb + kk,              lbA);
        async_copy16(gb + kk + 32,         lbA + 512);
        async_copy16(gb + 16384 + kk,      lbB);
        async_copy16(gb + 16384 + kk + 32, lbB + 512);
        __syncthreads();
#pragma unroll
        for (int kb = 0; kb < 2; kb++) {
            short8 af[4], bf[4];
#pragma unroll
            for (int mt = 0; mt < 4; mt++)
                af[mt] = *(const short8*)&lsA[(wm * 4 + mt) * 1024 + kb * 512 + l15 * 32 + quad * 8];
#pragma unroll
            for (int nt = 0; nt < 4; nt++)
                bf[nt] = *(const short8*)&lsB[(wn * 4 + nt) * 1024 + kb * 512 + l15 * 32 + quad * 8];
#pragma unroll
            for (int mt = 0; mt < 4; mt++)
#pragma unroll
                for (int nt = 0; nt < 4; nt++)
                    acc[mt][nt] = __builtin_amdgcn_mfma_f32_16x16x32_bf16(
                        af[mt], bf[nt], acc[mt][nt], 0, 0, 0);
        }
        __syncthreads();
    }
#pragma unroll
    for (int mt = 0; mt < 4; mt++) {
        const long rowb = m0 + wm * 64 + mt * 16 + quad * 4;
#pragma unroll
        for (int nt = 0; nt < 4; nt++) {
            const long col = n0 + wn * 64 + nt * 16 + l15;
#pragma unroll
            for (int r = 0; r < 4; r++)
                C[(rowb + r) * 256 + col] = acc[mt][nt][r];
        }
    }
}

// ---------------------------------------------------------------------------
// Per-token softmax over each router's 64 logits (= l0+l1+l2), scaled by
// importance, summed over tokens into w_raw[4][8][64] (fp32 atomics).
// ---------------------------------------------------------------------------
__global__ __launch_bounds__(128) void router_agg(
    const float* __restrict__ l0, const float* __restrict__ l1,
    const float* __restrict__ l2, const float* __restrict__ imp,
    float* __restrict__ w_raw)
{
    __shared__ float pref[32][257];
    const int tid = threadIdx.x;
    const int tl = tid >> 2, r = tid & 3;
    const int s = blockIdx.x * 32 + tl;
    const int b = s >> 10;
    const long off = (long)s * 256 + r * 64;
    float v[64];
#pragma unroll
    for (int i = 0; i < 16; i++) {
        float4 f0 = ((const float4*)(l0 + off))[i];
        float4 f1 = ((const float4*)(l1 + off))[i];
        float4 f2 = ((const float4*)(l2 + off))[i];
        v[i * 4 + 0] = f0.x + f1.x + f2.x;
        v[i * 4 + 1] = f0.y + f1.y + f2.y;
        v[i * 4 + 2] = f0.z + f1.z + f2.z;
        v[i * 4 + 3] = f0.w + f1.w + f2.w;
    }
    float mx = v[0];
#pragma unroll
    for (int i = 1; i < 64; i++) mx = fmaxf(mx, v[i]);
    float sum = 0.f;
#pragma unroll
    for (int i = 0; i < 64; i++) { v[i] = __expf(v[i] - mx); sum += v[i]; }
    const float scale = imp[s] / sum;
#pragma unroll
    for (int i = 0; i < 64; i++) pref[tl][r * 64 + i] = v[i] * scale;
    __syncthreads();
#pragma unroll
    for (int half = 0; half < 2; half++) {
        const int idx = tid + half * 128;
        const int r2 = idx >> 6, n = idx & 63;
        float acc = 0.f;
#pragma unroll 8
        for (int t = 0; t < 32; t++) acc += pref[t][r2 * 64 + n];
        atomicAdd(&w_raw[(r2 * 8 + b) * 64 + n], acc);
    }
}

// ---------------------------------------------------------------------------
// Normalize w, top-k (k=16 router 0, else 8), renormalize.
// ---------------------------------------------------------------------------
__global__ void topk_kernel(const float* __restrict__ w_raw,
                            float* __restrict__ topw, int* __restrict__ topi)
{
    const int r = blockIdx.x >> 3, b = blockIdx.x & 7;
    const int lane = threadIdx.x;
    const int k = (r == 0) ? 16 : 8;
    float w = w_raw[(r * 8 + b) * 64 + lane];
    float tot = w;
    for (int o2 = 32; o2 >= 1; o2 >>= 1) tot += __shfl_xor(tot, o2);
    w = w / (tot + 1e-8f);
    __shared__ float tw[16];
    __shared__ int ti[16];
    float cur = w;
    float ssum = 0.f;
    for (int j = 0; j < k; j++) {
        float m = cur; int mi = lane;
        for (int o2 = 32; o2 >= 1; o2 >>= 1) {
            float om = __shfl_xor(m, o2); int oi = __shfl_xor(mi, o2);
            if (om > m || (om == m && oi < mi)) { m = om; mi = oi; }
        }
        if (lane == 0) { tw[j] = m; ti[j] = mi; }
        ssum += m;
        if (lane == mi) cur = -1e30f;
    }
    __syncthreads();
    if (lane < 16) {
        topw[(r * 8 + b) * 16 + lane] = (lane < k) ? tw[lane] / (ssum + 1e-8f) : 0.f;
        topi[(r * 8 + b) * 16 + lane] = (lane < k) ? ti[lane] : 0;
    }
}

// ---------------------------------------------------------------------------
// out[b][j][i] = sum_k w[b,k] * pool[idx[b,k]][i][j]   (transposing gather-mix)
// ---------------------------------------------------------------------------
__global__ __launch_bounds__(256) void gather_mix(
    const float* __restrict__ pool, const float* __restrict__ topw,
    const int* __restrict__ topi, u16* __restrict__ out,
    int I, int J, int k)
{
    __shared__ float tile[64][65];
    const int b = blockIdx.z;
    const long IJ = (long)I * J;
    const int i0 = blockIdx.x * 64, j0 = blockIdx.y * 64;
    const float* tw = topw + b * 16;
    const int* ti = topi + b * 16;
    const int tid = threadIdx.x;
    const int il = tid >> 2, jg = tid & 3;
    float acc[16];
#pragma unroll
    for (int m = 0; m < 16; m++) acc[m] = 0.f;
    for (int kk = 0; kk < k; kk++) {
        const float wgt = tw[kk];
        const long n = ti[kk];
        const float* src = pool + n * IJ + (long)(i0 + il) * J + j0 + jg * 16;
        float4 a0 = ((const float4*)src)[0];
        float4 a1 = ((const float4*)src)[1];
        float4 a2 = ((const float4*)src)[2];
        float4 a3 = ((const float4*)src)[3];
        acc[0] += wgt * a0.x;  acc[1] += wgt * a0.y;
        acc[2] += wgt * a0.z;  acc[3] += wgt * a0.w;
        acc[4] += wgt * a1.x;  acc[5] += wgt * a1.y;
        acc[6] += wgt * a1.z;  acc[7] += wgt * a1.w;
        acc[8] += wgt * a2.x;  acc[9] += wgt * a2.y;
        acc[10] += wgt * a2.z; acc[11] += wgt * a2.w;
        acc[12] += wgt * a3.x; acc[13] += wgt * a3.y;
        acc[14] += wgt * a3.z; acc[15] += wgt * a3.w;
    }
#pragma unroll
    for (int m = 0; m < 16; m++) tile[il][jg * 16 + m] = acc[m];
    __syncthreads();
    const int jl = tid >> 2, ig = tid & 3;
    short8 o0, o1;
#pragma unroll
    for (int m = 0; m < 8; m++) {
        o0[m] = (short)f2bf(tile[ig * 16 + m][jl]);
        o1[m] = (short)f2bf(tile[ig * 16 + 8 + m][jl]);
    }
    u16* dst = out + (long)b * IJ + (long)(j0 + jl) * I + i0 + ig * 16;
    *(short8*)dst = o0;
    *(short8*)(dst + 8) = o1;
}

// ---------------------------------------------------------------------------
// Merged eQ/eK/eV gather-mix (same pool, I=256, J=1024, k=8).
// z = r*8 + b; r selects router slice (1..3) and output.
// ---------------------------------------------------------------------------
__global__ __launch_bounds__(256) void gather_mix3(
    const float* __restrict__ pool, const float* __restrict__ topw,
    const int* __restrict__ topi, u16* __restrict__ eQT,
    u16* __restrict__ eKT, u16* __restrict__ eVT)
{
    __shared__ float tile[64][65];
    const int z = blockIdx.z;
    const int r = z >> 3, b = z & 7;
    u16* out = (r == 0) ? eQT : (r == 1) ? eKT : eVT;
    const long IJ = 262144;   // 256*1024
    const int i0 = blockIdx.x * 64, j0 = blockIdx.y * 64;
    const float* tw = topw + (1 + r) * 128 + b * 16;
    const int* ti = topi + (1 + r) * 128 + b * 16;
    const int tid = threadIdx.x;
    const int il = tid >> 2, jg = tid & 3;
    float acc[16];
#pragma unroll
    for (int m = 0; m < 16; m++) acc[m] = 0.f;
    for (int kk = 0; kk < 8; kk++) {
        const float wgt = tw[kk];
        const long n = ti[kk];
        const float* src = pool + n * IJ + (long)(i0 + il) * 1024 + j0 + jg * 16;
        float4 a0 = ((const float4*)src)[0];
        float4 a1 = ((const float4*)src)[1];
        float4 a2 = ((const float4*)src)[2];
        float4 a3 = ((const float4*)src)[3];
        acc[0] += wgt * a0.x;  acc[1] += wgt * a0.y;
        acc[2] += wgt * a0.z;  acc[3] += wgt * a0.w;
        acc[4] += wgt * a1.x;  acc[5] += wgt * a1.y;
        acc[6] += wgt * a1.z;  acc[7] += wgt * a1.w;
        acc[8] += wgt * a2.x;  acc[9] += wgt * a2.y;
        acc[10] += wgt * a2.z; acc[11] += wgt * a2.w;
        acc[12] += wgt * a3.x; acc[13] += wgt * a3.y;
        acc[14] += wgt * a3.z; acc[15] += wgt * a3.w;
    }
#pragma unroll
    for (int m = 0; m < 16; m++) tile[il][jg * 16 + m] = acc[m];
    __syncthreads();
    const int jl = tid >> 2, ig = tid & 3;
    short8 o0, o1;
#pragma unroll
    for (int m = 0; m < 8; m++) {
        o0[m] = (short)f2bf(tile[ig * 16 + m][jl]);
        o1[m] = (short)f2bf(tile[ig * 16 + 8 + m][jl]);
    }
    u16* dst = out + (long)b * IJ + (long)(j0 + jl) * 256 + i0 + ig * 16;
    *(short8*)dst = o0;
    *(short8*)(dst + 8) = o1;
}

// ---------------------------------------------------------------------------
// Causal flash attention, S^T formulation (R0 structure — best measured;
// frozen: every restructure lost on registers or the LDS pipe, and R9
// proved it is latency-bound, not memory-bound: FETCH 79->24.7MB with
// no time change). XCD swizzle + setprio kept (harmless, less HBM).
// ---------------------------------------------------------------------------
__global__ __launch_bounds__(256, 2) void flash_attn(
    const u16* __restrict__ Qg, const u16* __restrict__ Kg,
    const u16* __restrict__ Vt, u16* __restrict__ Og)
{
    __shared__ __align__(16) u16 plds[4][32 * 72];   // per-wave P, stride 72 u16
    const int tid = threadIdx.x;
    const int wv = tid >> 6, lane = tid & 63;
    const int quad = lane >> 4, l15 = lane & 15;
    const int p = blockIdx.x;                    // physical block 0..511
    const int bidx = (p & 7) * 64 + (p >> 3);    // XCD-contiguous logical block
    const int gw = bidx * 4 + wv;
    const int pr = gw & 15;
    const int bh = gw >> 4;                  // 0..127, same for all waves in block
    const int hh = bh & 15, bb = bh >> 4;
    const long SD = 1024L * 1024L;
    const u16* Qb = Qg + (long)bb * SD + hh * 64;
    const u16* Kb = Kg + (long)bb * SD + hh * 64;
    const u16* Vb = Vt + (long)bb * SD + (long)hh * 64 * 1024;
    u16* myp = plds[wv];

    for (int half = 0; half < 2; half++) {
        const int qt = half ? (31 - pr) : pr;
        const int q0 = qt * 32;

        short8 qf[2][2];
#pragma unroll
        for (int mt = 0; mt < 2; mt++)
#pragma unroll
            for (int kb = 0; kb < 2; kb++)
                qf[mt][kb] = *(const short8*)(Qb + (long)(q0 + mt * 16 + l15) * 1024 + kb * 32 + quad * 8);

        f32x4 o[2][4];
        float mrow[2] = {-3e38f, -3e38f}, lrow[2] = {0.f, 0.f};
#pragma unroll
        for (int mt = 0; mt < 2; mt++)
#pragma unroll
            for (int nt = 0; nt < 4; nt++) o[mt][nt] = (f32x4){0.f, 0.f, 0.f, 0.f};

        const int ntile = (q0 + 95) >> 6;    // ceil((q0+32)/64)
        short8 kf[4][2], kn[4][2];
#pragma unroll
        for (int kt = 0; kt < 4; kt++)
#pragma unroll
            for (int kb = 0; kb < 2; kb++)
                kf[kt][kb] = *(const short8*)(Kb + (long)(kt * 16 + l15) * 1024 + kb * 32 + quad * 8);

        for (int it = 0; it < ntile; it++) {
            const int k2 = it * 64;
            const bool last = (it == ntile - 1);
            // S^T[key][q] = K·Q^T
            f32x4 st[4][2];
            __builtin_amdgcn_s_setprio(1);
#pragma unroll
            for (int kt = 0; kt < 4; kt++)
#pragma unroll
                for (int q_ = 0; q_ < 2; q_++) {
                    f32x4 z = (f32x4){0.f, 0.f, 0.f, 0.f};
                    z = __builtin_amdgcn_mfma_f32_16x16x32_bf16(kf[kt][0], qf[q_][0], z, 0, 0, 0);
                    z = __builtin_amdgcn_mfma_f32_16x16x32_bf16(kf[kt][1], qf[q_][1], z, 0, 0, 0);
                    st[kt][q_] = z;
                }
            __builtin_amdgcn_s_setprio(0);
            // V loads for this iter (latency hidden under softmax)
            short8 vf[4][2];
#pragma unroll
            for (int nt = 0; nt < 4; nt++)
#pragma unroll
                for (int kh = 0; kh < 2; kh++)
                    vf[nt][kh] = *(const short8*)(Vb + (long)(nt * 16 + l15) * 1024 + k2 + kh * 32 + quad * 8);
            // prefetch next K tile
            if (it + 1 < ntile) {
#pragma unroll
                for (int kt = 0; kt < 4; kt++)
#pragma unroll
                    for (int kb = 0; kb < 2; kb++)
                        kn[kt][kb] = *(const short8*)(Kb + (long)(k2 + 64 + kt * 16 + l15) * 1024 + kb * 32 + quad * 8);
            }
            // online softmax per q-column (lane&15 holds q)
            float am[2];
#pragma unroll
            for (int q_ = 0; q_ < 2; q_++) {
                if (last) {
#pragma unroll
                    for (int kt = 0; kt < 4; kt++)
#pragma unroll
                        for (int r = 0; r < 4; r++)
                            if (k2 + kt * 16 + quad * 4 + r > q0 + q_ * 16 + l15)
                                st[kt][q_][r] = -3e38f;
                }
                // balanced max tree (exact)
                float t0 = fmaxf(fmaxf(st[0][q_][0], st[0][q_][1]), fmaxf(st[0][q_][2], st[0][q_][3]));
                float t1 = fmaxf(fmaxf(st[1][q_][0], st[1][q_][1]), fmaxf(st[1][q_][2], st[1][q_][3]));
                float t2 = fmaxf(fmaxf(st[2][q_][0], st[2][q_][1]), fmaxf(st[2][q_][2], st[2][q_][3]));
                float t3 = fmaxf(fmaxf(st[3][q_][0], st[3][q_][1]), fmaxf(st[3][q_][2], st[3][q_][3]));
                float cm = fmaxf(fmaxf(t0, t1), fmaxf(t2, t3));
                cm = fmaxf(cm, __shfl_xor(cm, 16));
                cm = fmaxf(cm, __shfl_xor(cm, 32));
                const float mn = fmaxf(mrow[q_], cm);
                am[q_] = exp2f(mrow[q_] - mn);
                mrow[q_] = mn;
                // fold +log2(1+2^-9) so the truncating bf16 pack is ~unbiased
                const float moff = 0.00281502f - mn;
                float s4[4];
#pragma unroll
                for (int kt = 0; kt < 4; kt++) {
                    float p0 = exp2f(st[kt][q_][0] + moff);
                    float p1 = exp2f(st[kt][q_][1] + moff);
                    float p2 = exp2f(st[kt][q_][2] + moff);
                    float p3 = exp2f(st[kt][q_][3] + moff);
                    s4[kt] = (p0 + p1) + (p2 + p3);
                    u32 w0 = pack_bf(p0, p1);
                    u32 w1 = pack_bf(p2, p3);
                    *(uint2*)&myp[(q_ * 16 + l15) * 72 + kt * 16 + quad * 4] = make_uint2(w0, w1);
                }
                float rs = (s4[0] + s4[1]) + (s4[2] + s4[3]);
                rs += __shfl_xor(rs, 16);
                rs += __shfl_xor(rs, 32);
                lrow[q_] = lrow[q_] * am[q_] + rs;
            }
            // redistribute alpha from q-on-l15 to q-on-row layout
            float av[2][4];
#pragma unroll
            for (int mt = 0; mt < 2; mt++)
#pragma unroll
                for (int r = 0; r < 4; r++)
                    av[mt][r] = __shfl(am[mt], quad * 4 + r);
            asm volatile("s_waitcnt lgkmcnt(0)" ::: "memory");
            short8 pf0[2], pf1[2];
#pragma unroll
            for (int kh = 0; kh < 2; kh++) {
                pf0[kh] = *(const short8*)&myp[(l15) * 72 + kh * 32 + quad * 8];
                pf1[kh] = *(const short8*)&myp[(16 + l15) * 72 + kh * 32 + quad * 8];
            }
#pragma unroll
            for (int mt = 0; mt < 2; mt++)
#pragma unroll
                for (int nt = 0; nt < 4; nt++)
#pragma unroll
                    for (int r = 0; r < 4; r++) o[mt][nt][r] *= av[mt][r];
            __builtin_amdgcn_s_setprio(1);
#pragma unroll
            for (int nt = 0; nt < 4; nt++)
#pragma unroll
                for (int kh = 0; kh < 2; kh++) {
                    o[0][nt] = __builtin_amdgcn_mfma_f32_16x16x32_bf16(pf0[kh], vf[nt][kh], o[0][nt], 0, 0, 0);
                    o[1][nt] = __builtin_amdgcn_mfma_f32_16x16x32_bf16(pf1[kh], vf[nt][kh], o[1][nt], 0, 0, 0);
                }
            __builtin_amdgcn_s_setprio(0);
            if (it + 1 < ntile) {
#pragma unroll
                for (int kt = 0; kt < 4; kt++)
#pragma unroll
                    for (int kb = 0; kb < 2; kb++) kf[kt][kb] = kn[kt][kb];
            }
        }
        // epilogue
#pragma unroll
        for (int mt = 0; mt < 2; mt++)
#pragma unroll
            for (int r = 0; r < 4; r++) {
                const float li = 1.0f / __shfl(lrow[mt], quad * 4 + r);
                const long row = q0 + mt * 16 + quad * 4 + r;
#pragma unroll
                for (int nt = 0; nt < 4; nt++)
                    Og[(long)bb * SD + row * 1024 + hh * 64 + nt * 16 + l15] =
                        f2bf(o[mt][nt][r] * li);
            }
    }
}

// ---------------------------------------------------------------------------
extern "C" void kernel_launch(void* const* d_in, const int* in_sizes, int n_in,
                              void* d_out, int out_size, void* d_ws, size_t ws_size,
                              hipStream_t stream)
{
    const float* x   = (const float*)d_in[0];
    const float* imp = (const float*)d_in[1];
    const float* cn  = (const float*)d_in[6];
    const float* ep  = (const float*)d_in[7];
    const float* Wo  = (const float*)d_in[8];
    float* outp = (float*)d_out;
    char* ws = (char*)d_ws;

    // d_out (33.55 MB) doubles as scratch for x_hi/x_lo until the final GEMM.
    u16* xh = (u16*)d_out;                    // [8192][1024] bf16
    u16* xl = xh + 8388608;                   // [8192][1024] bf16

    u16*   Wh     = (u16*)(ws + 0);           // [256][1024] bf16
    u16*   Wl     = (u16*)(ws + 524288);      // [256][1024] bf16
    u16*   Wobf   = (u16*)(ws + 1048576);     // [1024][1024] bf16
    float* w_raw  = (float*)(ws + 3145728);   // [4][8][64]
    float* topw   = (float*)(ws + 3153920);   // [4][8][16]
    int*   topi   = (int*)(ws + 3155968);     // [4][8][16]
    // logits seg buffers: L0 in the pre-Kb region; L1/L2 park in the Qb
    // region (both dead before gemm_qkv writes Qb).
    float* logit0 = (float*)(ws + 4194304);   // [8192][256] fp32
    float* logit1 = (float*)(ws + 33554432);  // [8192][256] fp32 (Qb region)
    float* logit2 = (float*)(ws + 41943040);  // [8192][256] fp32 (Qb region)
    u16*   scT    = (u16*)(ws + 12582912);    // [8][256][1024] (dead after h GEMM)
    u16*   eQT    = (u16*)(ws + 16777216);    // [8][1024][256] (dead after QKV GEMM)
    u16*   Kb     = (u16*)(ws + 4194304);     // [8][1024][1024] (written after logits die)
    u16*   hbuf   = (u16*)(ws + 20971520);    // [8][1024][256]
    u16*   eKT    = (u16*)(ws + 25165824);    // [8][1024][256]
    u16*   eVT    = (u16*)(ws + 29360128);    // [8][1024][256]
    u16*   Qb     = (u16*)(ws + 33554432);    // [8][1024][1024]
    u16*   VTb    = (u16*)(ws + 50331648);    // [8][1024(D)][1024(S)]
    u16*   aout   = (u16*)(ws + 67108864);    // [8][1024][1024]

    // 0) precision splits / conversions
    cvt_split<<<dim3(8192), 256, 0, stream>>>(x, xh, xl, 2097152);
    cvt_split_w4<<<dim3(256), 256, 0, stream>>>(
        (const float*)d_in[2], (const float*)d_in[3],
        (const float*)d_in[4], (const float*)d_in[5], Wh, Wl);
    cvt_bf<<<dim3(1024), 256, 0, stream>>>(Wo, Wobf, 262144);
    hipMemsetAsync(w_raw, 0, 4 * 8 * 64 * 4, stream);

    // 1) router logits, split-bf16, one segment per z (384 blocks, BK=64)
    gemm_router<<<dim3(64, 2, 3), 256, 0, stream>>>(
        xh, xl, Wh, Wl, logit0, logit1, logit2);
    // 2) softmax + importance aggregation, 3) top-k (all fp32)
    router_agg<<<dim3(256), 128, 0, stream>>>(logit0, logit1, logit2, imp, w_raw);
    topk_kernel<<<dim3(32), 64, 0, stream>>>(w_raw, topw, topi);
    // 4) gathered expert mixes (fp32 pools -> bf16, stored transposed/K-contig)
    gather_mix<<<dim3(16, 4, 8), 256, 0, stream>>>(cn, topw + 0 * 128, topi + 0 * 128, scT, 1024, 256, 16);
    gather_mix3<<<dim3(4, 16, 24), 256, 0, stream>>>(ep, topw, topi, eQT, eKT, eVT);
    // 5) h[b] = x[b] @ scT[b]^T   (M=1024,N=256,K=1024, BK=64)
    gemm_bt<u16><<<dim3(8, 2, 8), 256, 0, stream>>>(
        xh, 1024, 1048576, scT, 1024, 262144, hbuf, 256, 262144, 1024, 1.0f);
    // 6) Q/K/V^T in one launch (1536 blocks, BK=64 -> 4 K-steps)
    gemm_qkv<<<dim3(8, 8, 24), 256, 0, stream>>>(hbuf, eQT, eKT, eVT, Qb, Kb, VTb);
    // 7) causal flash attention (512 blocks, XCD-grouped (b,h) sharing)
    flash_attn<<<dim3(512), 256, 0, stream>>>(Qb, Kb, VTb, aout);
    // 8) output projection: out = aout @ W_O^T (fp32 out, BK=64)
    gemm_bt<float><<<dim3(64, 8, 1), 256, 0, stream>>>(
        aout, 1024, 0, Wobf, 1024, 0, outp, 1024, 0, 1024, 1.0f);
}

// Round 11
// 397.949 us; speedup vs baseline: 1.0461x; 1.0158x over previous
//
#include <hip/hip_runtime.h>

typedef __attribute__((ext_vector_type(8))) short short8;
typedef __attribute__((ext_vector_type(4))) short short4v;
typedef __attribute__((ext_vector_type(4))) float f32x4;
typedef unsigned short u16;
typedef unsigned int u32;

__device__ __forceinline__ float bf2f(u16 h) {
    return __uint_as_float(((u32)h) << 16);
}
__device__ __forceinline__ u16 f2bf(float f) {
    u32 u = __float_as_uint(f);
    u32 r = u + 0x7fffu + ((u >> 16) & 1u);   // RNE
    return (u16)(r >> 16);
}
// pack hi16(a), hi16(b) -> (b.hi<<16)|a.hi  (truncating bf16 pack, 1 instr)
__device__ __forceinline__ u32 pack_bf(float a, float b) {
    return __builtin_amdgcn_perm(__float_as_uint(b), __float_as_uint(a), 0x07060302u);
}

__device__ __forceinline__ void async_copy16(const void* g, void* l) {
    __builtin_amdgcn_global_load_lds(
        (const __attribute__((address_space(1))) void*)g,
        (__attribute__((address_space(3))) void*)l, 16, 0, 0);
}

// ---------------------------------------------------------------------------
// fp32 -> (bf16 hi, bf16 lo) split conversion. lo = bf16(v - f(hi)).
// ---------------------------------------------------------------------------
__global__ __launch_bounds__(256) void cvt_split(
    const float* __restrict__ in, u16* __restrict__ hi, u16* __restrict__ lo, int n4)
{
    int i = blockIdx.x * 256 + threadIdx.x;
    if (i >= n4) return;
    float4 v = ((const float4*)in)[i];
    short4v h, l;
    float vv[4] = {v.x, v.y, v.z, v.w};
#pragma unroll
    for (int j = 0; j < 4; j++) {
        u16 hb = f2bf(vv[j]);
        h[j] = (short)hb;
        l[j] = (short)f2bf(vv[j] - bf2f(hb));
    }
    ((short4v*)hi)[i] = h;
    ((short4v*)lo)[i] = l;
}

// 4 router weight matrices in one launch: 64 blocks per router.
__global__ __launch_bounds__(256) void cvt_split_w4(
    const float* __restrict__ w0, const float* __restrict__ w1,
    const float* __restrict__ w2, const float* __restrict__ w3,
    u16* __restrict__ hi, u16* __restrict__ lo)
{
    const int r = blockIdx.x >> 6;
    const float* src = (r == 0) ? w0 : (r == 1) ? w1 : (r == 2) ? w2 : w3;
    int i = (blockIdx.x & 63) * 256 + threadIdx.x;   // < 16384 float4s
    float4 v = ((const float4*)src)[i];
    short4v h, l;
    float vv[4] = {v.x, v.y, v.z, v.w};
#pragma unroll
    for (int j = 0; j < 4; j++) {
        u16 hb = f2bf(vv[j]);
        h[j] = (short)hb;
        l[j] = (short)f2bf(vv[j] - bf2f(hb));
    }
    ((short4v*)(hi + (long)r * 65536))[i] = h;
    ((short4v*)(lo + (long)r * 65536))[i] = l;
}

__global__ __launch_bounds__(256) void cvt_bf(
    const float* __restrict__ in, u16* __restrict__ out, int n4)
{
    int i = blockIdx.x * 256 + threadIdx.x;
    if (i >= n4) return;
    float4 v = ((const float4*)in)[i];
    short4v h;
    h[0] = (short)f2bf(v.x); h[1] = (short)f2bf(v.y);
    h[2] = (short)f2bf(v.z); h[3] = (short)f2bf(v.w);
    ((short4v*)out)[i] = h;
}

// ---------------------------------------------------------------------------
// bf16 GEMM: C[M][N] = cscale * (A[M][K] * B[N][K]^T). m97 structure,
// templated K-step BK (32 | 64 | 128). BK=128 for the K=1024 call sites:
// those grids are <=2 blocks/CU (grid-limited), so the 64KB LDS costs no
// occupancy while halving the barrier+vmcnt-drain count vs BK=64.
// MFMA order identical for any BK -> bitwise-same accumulation.
// ---------------------------------------------------------------------------
template <typename CT, int BK>
__global__ __launch_bounds__(256) void gemm_bt(
    const u16* __restrict__ A, long lda, long bsA,
    const u16* __restrict__ Bm, long ldb, long bsB,
    CT* __restrict__ C, long ldc, long bsC, int K, float cscale)
{
    constexpr int NC = BK / 32;            // 512-u16 k-chunks per 16-row block
    constexpr int RB = 16 * BK;            // u16 per 16-row block
    __shared__ __align__(16) u16 lsA[128 * BK];
    __shared__ __align__(16) u16 lsB[128 * BK];
    const int tid = threadIdx.x;
    const int wave = tid >> 6, lane = tid & 63;
    const int quad = lane >> 4, l15 = lane & 15;
    const int wm = wave >> 1, wn = wave & 1;
    const long m0 = (long)blockIdx.x * 128, n0 = (long)blockIdx.y * 128;
    A  += (long)blockIdx.z * bsA;
    Bm += (long)blockIdx.z * bsB;
    C  += (long)blockIdx.z * bsC;
    const int srow = lane >> 2, scol = (lane & 3) * 8;

    f32x4 acc[4][4];
#pragma unroll
    for (int i = 0; i < 4; i++)
#pragma unroll
        for (int j = 0; j < 4; j++) acc[i][j] = (f32x4){0.f, 0.f, 0.f, 0.f};

    const u16* ga0 = A + (m0 + (wave * 2 + 0) * 16 + srow) * lda + scol;
    const u16* ga1 = A + (m0 + (wave * 2 + 1) * 16 + srow) * lda + scol;
    const u16* gb0 = Bm + (n0 + (wave * 2 + 0) * 16 + srow) * ldb + scol;
    const u16* gb1 = Bm + (n0 + (wave * 2 + 1) * 16 + srow) * ldb + scol;
    u16* laA = &lsA[(wave * 2 + 0) * RB];
    u16* laB = &lsA[(wave * 2 + 1) * RB];
    u16* lbA = &lsB[(wave * 2 + 0) * RB];
    u16* lbB = &lsB[(wave * 2 + 1) * RB];

    for (int kk = 0; kk < K; kk += BK) {
#pragma unroll
        for (int c = 0; c < NC; c++) {
            async_copy16(ga0 + kk + c * 32, laA + c * 512);
            async_copy16(ga1 + kk + c * 32, laB + c * 512);
            async_copy16(gb0 + kk + c * 32, lbA + c * 512);
            async_copy16(gb1 + kk + c * 32, lbB + c * 512);
        }
        __syncthreads();
#pragma unroll
        for (int kb = 0; kb < NC; kb++) {
            short8 af[4], bf[4];
#pragma unroll
            for (int mt = 0; mt < 4; mt++)
                af[mt] = *(const short8*)&lsA[(wm * 4 + mt) * RB + kb * 512 + l15 * 32 + quad * 8];
#pragma unroll
            for (int nt = 0; nt < 4; nt++)
                bf[nt] = *(const short8*)&lsB[(wn * 4 + nt) * RB + kb * 512 + l15 * 32 + quad * 8];
#pragma unroll
            for (int mt = 0; mt < 4; mt++)
#pragma unroll
                for (int nt = 0; nt < 4; nt++)
                    acc[mt][nt] = __builtin_amdgcn_mfma_f32_16x16x32_bf16(
                        af[mt], bf[nt], acc[mt][nt], 0, 0, 0);
        }
        __syncthreads();
    }
#pragma unroll
    for (int mt = 0; mt < 4; mt++) {
        const long rowb = m0 + wm * 64 + mt * 16 + quad * 4;
#pragma unroll
        for (int nt = 0; nt < 4; nt++) {
            const long col = n0 + wn * 64 + nt * 16 + l15;
#pragma unroll
            for (int r = 0; r < 4; r++) {
                const float v = acc[mt][nt][r] * cscale;
                if constexpr (sizeof(CT) == 2)
                    C[(rowb + r) * ldc + col] = f2bf(v);
                else
                    C[(rowb + r) * ldc + col] = v;
            }
        }
    }
}

// ---------------------------------------------------------------------------
// Merged Q/K/V^T projection GEMMs, BK=64 (kept: 1536 blocks = 6/CU wants
// the 32KB-LDS occupancy). All three are M=1024, N=1024, K=256.
// z = sel*8 + batch; sel: 0=Q, 1=K, 2=V^T.
// ---------------------------------------------------------------------------
__global__ __launch_bounds__(256) void gemm_qkv(
    const u16* __restrict__ hbuf, const u16* __restrict__ eQT,
    const u16* __restrict__ eKT, const u16* __restrict__ eVT,
    u16* __restrict__ Qb, u16* __restrict__ Kb, u16* __restrict__ VTb)
{
    __shared__ __align__(16) u16 lsA[128 * 64];
    __shared__ __align__(16) u16 lsB[128 * 64];
    const int z = blockIdx.z;
    const int sel = z >> 3, bbz = z & 7;
    const long ab = (long)bbz * 262144;
    const u16* A  = ((sel == 2) ? eVT : hbuf) + ab;
    const u16* Bm = ((sel == 0) ? eQT : (sel == 1) ? eKT : hbuf) + ab;
    u16* C = ((sel == 0) ? Qb : (sel == 1) ? Kb : VTb) + (long)bbz * 1048576;
    const float cscale = (sel == 0) ? 0.180336880111f : 1.0f;

    const int tid = threadIdx.x;
    const int wave = tid >> 6, lane = tid & 63;
    const int quad = lane >> 4, l15 = lane & 15;
    const int wm = wave >> 1, wn = wave & 1;
    const long m0 = (long)blockIdx.x * 128, n0 = (long)blockIdx.y * 128;
    const int srow = lane >> 2, scol = (lane & 3) * 8;

    f32x4 acc[4][4];
#pragma unroll
    for (int i = 0; i < 4; i++)
#pragma unroll
        for (int j = 0; j < 4; j++) acc[i][j] = (f32x4){0.f, 0.f, 0.f, 0.f};

    const u16* ga0 = A + (m0 + (wave * 2 + 0) * 16 + srow) * 256 + scol;
    const u16* ga1 = A + (m0 + (wave * 2 + 1) * 16 + srow) * 256 + scol;
    const u16* gb0 = Bm + (n0 + (wave * 2 + 0) * 16 + srow) * 256 + scol;
    const u16* gb1 = Bm + (n0 + (wave * 2 + 1) * 16 + srow) * 256 + scol;
    u16* laA = &lsA[(wave * 2 + 0) * 1024];
    u16* laB = &lsA[(wave * 2 + 1) * 1024];
    u16* lbA = &lsB[(wave * 2 + 0) * 1024];
    u16* lbB = &lsB[(wave * 2 + 1) * 1024];

    for (int kk = 0; kk < 256; kk += 64) {
        async_copy16(ga0 + kk,      laA);
        async_copy16(ga0 + kk + 32, laA + 512);
        async_copy16(ga1 + kk,      laB);
        async_copy16(ga1 + kk + 32, laB + 512);
        async_copy16(gb0 + kk,      lbA);
        async_copy16(gb0 + kk + 32, lbA + 512);
        async_copy16(gb1 + kk,      lbB);
        async_copy16(gb1 + kk + 32, lbB + 512);
        __syncthreads();
#pragma unroll
        for (int kb = 0; kb < 2; kb++) {
            short8 af[4], bf[4];
#pragma unroll
            for (int mt = 0; mt < 4; mt++)
                af[mt] = *(const short8*)&lsA[(wm * 4 + mt) * 1024 + kb * 512 + l15 * 32 + quad * 8];
#pragma unroll
            for (int nt = 0; nt < 4; nt++)
                bf[nt] = *(const short8*)&lsB[(wn * 4 + nt) * 1024 + kb * 512 + l15 * 32 + quad * 8];
#pragma unroll
            for (int mt = 0; mt < 4; mt++)
#pragma unroll
                for (int nt = 0; nt < 4; nt++)
                    acc[mt][nt] = __builtin_amdgcn_mfma_f32_16x16x32_bf16(
                        af[mt], bf[nt], acc[mt][nt], 0, 0, 0);
        }
        __syncthreads();
    }
#pragma unroll
    for (int mt = 0; mt < 4; mt++) {
        const long rowb = m0 + wm * 64 + mt * 16 + quad * 4;
#pragma unroll
        for (int nt = 0; nt < 4; nt++) {
            const long col = n0 + wn * 64 + nt * 16 + l15;
#pragma unroll
            for (int r = 0; r < 4; r++)
                C[(rowb + r) * 1024 + col] = f2bf(acc[mt][nt][r] * cscale);
        }
    }
}

// ---------------------------------------------------------------------------
// Split-bf16 router logits, BK=128 (grid 384 = 1.5/CU is grid-limited;
// 64KB LDS costs nothing, halves barriers). One precision segment per z:
// seg0 = Ah*Bh^T -> C0, seg1 = Al*Bh^T -> C1, seg2 = Ah*Bl^T -> C2.
// ---------------------------------------------------------------------------
__global__ __launch_bounds__(256) void gemm_router(
    const u16* __restrict__ Ah, const u16* __restrict__ Al,
    const u16* __restrict__ Bh, const u16* __restrict__ Bl,
    float* __restrict__ C0, float* __restrict__ C1, float* __restrict__ C2)
{
    __shared__ __align__(16) u16 lsA[128 * 128];
    __shared__ __align__(16) u16 lsB[128 * 128];
    const int seg = blockIdx.z;
    const u16* A = (seg == 1) ? Al : Ah;
    const u16* B = (seg == 2) ? Bl : Bh;
    float* C = (seg == 0) ? C0 : (seg == 1) ? C1 : C2;
    const int tid = threadIdx.x;
    const int wave = tid >> 6, lane = tid & 63;
    const int quad = lane >> 4, l15 = lane & 15;
    const int wm = wave >> 1, wn = wave & 1;
    const long m0 = (long)blockIdx.x * 128, n0 = (long)blockIdx.y * 128;
    const int srow = lane >> 2, scol = (lane & 3) * 8;
    const u16* ga = A + (m0 + (wave * 2) * 16 + srow) * 1024 + scol;
    const u16* gb = B + (n0 + (wave * 2) * 16 + srow) * 1024 + scol;
    u16* laA = &lsA[(wave * 2 + 0) * 2048];
    u16* laB = &lsA[(wave * 2 + 1) * 2048];
    u16* lbA = &lsB[(wave * 2 + 0) * 2048];
    u16* lbB = &lsB[(wave * 2 + 1) * 2048];

    f32x4 acc[4][4];
#pragma unroll
    for (int i = 0; i < 4; i++)
#pragma unroll
        for (int j = 0; j < 4; j++) acc[i][j] = (f32x4){0.f, 0.f, 0.f, 0.f};

    for (int kk = 0; kk < 1024; kk += 128) {
#pragma unroll
        for (int c = 0; c < 4; c++) {
            async_copy16(ga + kk + c * 32,         laA + c * 512);
            async_copy16(ga + 16384 + kk + c * 32, laB + c * 512);
            async_copy16(gb + kk + c * 32,         lbA + c * 512);
            async_copy16(gb + 16384 + kk + c * 32, lbB + c * 512);
        }
        __syncthreads();
#pragma unroll
        for (int kb = 0; kb < 4; kb++) {
            short8 af[4], bf[4];
#pragma unroll
            for (int mt = 0; mt < 4; mt++)
                af[mt] = *(const short8*)&lsA[(wm * 4 + mt) * 2048 + kb * 512 + l15 * 32 + quad * 8];
#pragma unroll
            for (int nt = 0; nt < 4; nt++)
                bf[nt] = *(const short8*)&lsB[(wn * 4 + nt) * 2048 + kb * 512 + l15 * 32 + quad * 8];
#pragma unroll
            for (int mt = 0; mt < 4; mt++)
#pragma unroll
                for (int nt = 0; nt < 4; nt++)
                    acc[mt][nt] = __builtin_amdgcn_mfma_f32_16x16x32_bf16(
                        af[mt], bf[nt], acc[mt][nt], 0, 0, 0);
        }
        __syncthreads();
    }
#pragma unroll
    for (int mt = 0; mt < 4; mt++) {
        const long rowb = m0 + wm * 64 + mt * 16 + quad * 4;
#pragma unroll
        for (int nt = 0; nt < 4; nt++) {
            const long col = n0 + wn * 64 + nt * 16 + l15;
#pragma unroll
            for (int r = 0; r < 4; r++)
                C[(rowb + r) * 256 + col] = acc[mt][nt][r];
        }
    }
}

// ---------------------------------------------------------------------------
// Per-token softmax over each router's 64 logits (= l0+l1+l2), scaled by
// importance, summed over tokens into w_raw[4][8][64] (fp32 atomics).
// ---------------------------------------------------------------------------
__global__ __launch_bounds__(128) void router_agg(
    const float* __restrict__ l0, const float* __restrict__ l1,
    const float* __restrict__ l2, const float* __restrict__ imp,
    float* __restrict__ w_raw)
{
    __shared__ float pref[32][257];
    const int tid = threadIdx.x;
    const int tl = tid >> 2, r = tid & 3;
    const int s = blockIdx.x * 32 + tl;
    const int b = s >> 10;
    const long off = (long)s * 256 + r * 64;
    float v[64];
#pragma unroll
    for (int i = 0; i < 16; i++) {
        float4 f0 = ((const float4*)(l0 + off))[i];
        float4 f1 = ((const float4*)(l1 + off))[i];
        float4 f2 = ((const float4*)(l2 + off))[i];
        v[i * 4 + 0] = f0.x + f1.x + f2.x;
        v[i * 4 + 1] = f0.y + f1.y + f2.y;
        v[i * 4 + 2] = f0.z + f1.z + f2.z;
        v[i * 4 + 3] = f0.w + f1.w + f2.w;
    }
    float mx = v[0];
#pragma unroll
    for (int i = 1; i < 64; i++) mx = fmaxf(mx, v[i]);
    float sum = 0.f;
#pragma unroll
    for (int i = 0; i < 64; i++) { v[i] = __expf(v[i] - mx); sum += v[i]; }
    const float scale = imp[s] / sum;
#pragma unroll
    for (int i = 0; i < 64; i++) pref[tl][r * 64 + i] = v[i] * scale;
    __syncthreads();
#pragma unroll
    for (int half = 0; half < 2; half++) {
        const int idx = tid + half * 128;
        const int r2 = idx >> 6, n = idx & 63;
        float acc = 0.f;
#pragma unroll 8
        for (int t = 0; t < 32; t++) acc += pref[t][r2 * 64 + n];
        atomicAdd(&w_raw[(r2 * 8 + b) * 64 + n], acc);
    }
}

// ---------------------------------------------------------------------------
// Normalize w, top-k (k=16 router 0, else 8), renormalize.
// ---------------------------------------------------------------------------
__global__ void topk_kernel(const float* __restrict__ w_raw,
                            float* __restrict__ topw, int* __restrict__ topi)
{
    const int r = blockIdx.x >> 3, b = blockIdx.x & 7;
    const int lane = threadIdx.x;
    const int k = (r == 0) ? 16 : 8;
    float w = w_raw[(r * 8 + b) * 64 + lane];
    float tot = w;
    for (int o2 = 32; o2 >= 1; o2 >>= 1) tot += __shfl_xor(tot, o2);
    w = w / (tot + 1e-8f);
    __shared__ float tw[16];
    __shared__ int ti[16];
    float cur = w;
    float ssum = 0.f;
    for (int j = 0; j < k; j++) {
        float m = cur; int mi = lane;
        for (int o2 = 32; o2 >= 1; o2 >>= 1) {
            float om = __shfl_xor(m, o2); int oi = __shfl_xor(mi, o2);
            if (om > m || (om == m && oi < mi)) { m = om; mi = oi; }
        }
        if (lane == 0) { tw[j] = m; ti[j] = mi; }
        ssum += m;
        if (lane == mi) cur = -1e30f;
    }
    __syncthreads();
    if (lane < 16) {
        topw[(r * 8 + b) * 16 + lane] = (lane < k) ? tw[lane] / (ssum + 1e-8f) : 0.f;
        topi[(r * 8 + b) * 16 + lane] = (lane < k) ? ti[lane] : 0;
    }
}

// ---------------------------------------------------------------------------
// out[b][j][i] = sum_k w[b,k] * pool[idx[b,k]][i][j]   (transposing gather-mix)
// ---------------------------------------------------------------------------
__global__ __launch_bounds__(256) void gather_mix(
    const float* __restrict__ pool, const float* __restrict__ topw,
    const int* __restrict__ topi, u16* __restrict__ out,
    int I, int J, int k)
{
    __shared__ float tile[64][65];
    const int b = blockIdx.z;
    const long IJ = (long)I * J;
    const int i0 = blockIdx.x * 64, j0 = blockIdx.y * 64;
    const float* tw = topw + b * 16;
    const int* ti = topi + b * 16;
    const int tid = threadIdx.x;
    const int il = tid >> 2, jg = tid & 3;
    float acc[16];
#pragma unroll
    for (int m = 0; m < 16; m++) acc[m] = 0.f;
    for (int kk = 0; kk < k; kk++) {
        const float wgt = tw[kk];
        const long n = ti[kk];
        const float* src = pool + n * IJ + (long)(i0 + il) * J + j0 + jg * 16;
        float4 a0 = ((const float4*)src)[0];
        float4 a1 = ((const float4*)src)[1];
        float4 a2 = ((const float4*)src)[2];
        float4 a3 = ((const float4*)src)[3];
        acc[0] += wgt * a0.x;  acc[1] += wgt * a0.y;
        acc[2] += wgt * a0.z;  acc[3] += wgt * a0.w;
        acc[4] += wgt * a1.x;  acc[5] += wgt * a1.y;
        acc[6] += wgt * a1.z;  acc[7] += wgt * a1.w;
        acc[8] += wgt * a2.x;  acc[9] += wgt * a2.y;
        acc[10] += wgt * a2.z; acc[11] += wgt * a2.w;
        acc[12] += wgt * a3.x; acc[13] += wgt * a3.y;
        acc[14] += wgt * a3.z; acc[15] += wgt * a3.w;
    }
#pragma unroll
    for (int m = 0; m < 16; m++) tile[il][jg * 16 + m] = acc[m];
    __syncthreads();
    const int jl = tid >> 2, ig = tid & 3;
    short8 o0, o1;
#pragma unroll
    for (int m = 0; m < 8; m++) {
        o0[m] = (short)f2bf(tile[ig * 16 + m][jl]);
        o1[m] = (short)f2bf(tile[ig * 16 + 8 + m][jl]);
    }
    u16* dst = out + (long)b * IJ + (long)(j0 + jl) * I + i0 + ig * 16;
    *(short8*)dst = o0;
    *(short8*)(dst + 8) = o1;
}

// ---------------------------------------------------------------------------
// Merged eQ/eK/eV gather-mix (same pool, I=256, J=1024, k=8).
// z = r*8 + b; r selects router slice (1..3) and output.
// ---------------------------------------------------------------------------
__global__ __launch_bounds__(256) void gather_mix3(
    const float* __restrict__ pool, const float* __restrict__ topw,
    const int* __restrict__ topi, u16* __restrict__ eQT,
    u16* __restrict__ eKT, u16* __restrict__ eVT)
{
    __shared__ float tile[64][65];
    const int z = blockIdx.z;
    const int r = z >> 3, b = z & 7;
    u16* out = (r == 0) ? eQT : (r == 1) ? eKT : eVT;
    const long IJ = 262144;   // 256*1024
    const int i0 = blockIdx.x * 64, j0 = blockIdx.y * 64;
    const float* tw = topw + (1 + r) * 128 + b * 16;
    const int* ti = topi + (1 + r) * 128 + b * 16;
    const int tid = threadIdx.x;
    const int il = tid >> 2, jg = tid & 3;
    float acc[16];
#pragma unroll
    for (int m = 0; m < 16; m++) acc[m] = 0.f;
    for (int kk = 0; kk < 8; kk++) {
        const float wgt = tw[kk];
        const long n = ti[kk];
        const float* src = pool + n * IJ + (long)(i0 + il) * 1024 + j0 + jg * 16;
        float4 a0 = ((const float4*)src)[0];
        float4 a1 = ((const float4*)src)[1];
        float4 a2 = ((const float4*)src)[2];
        float4 a3 = ((const float4*)src)[3];
        acc[0] += wgt * a0.x;  acc[1] += wgt * a0.y;
        acc[2] += wgt * a0.z;  acc[3] += wgt * a0.w;
        acc[4] += wgt * a1.x;  acc[5] += wgt * a1.y;
        acc[6] += wgt * a1.z;  acc[7] += wgt * a1.w;
        acc[8] += wgt * a2.x;  acc[9] += wgt * a2.y;
        acc[10] += wgt * a2.z; acc[11] += wgt * a2.w;
        acc[12] += wgt * a3.x; acc[13] += wgt * a3.y;
        acc[14] += wgt * a3.z; acc[15] += wgt * a3.w;
    }
#pragma unroll
    for (int m = 0; m < 16; m++) tile[il][jg * 16 + m] = acc[m];
    __syncthreads();
    const int jl = tid >> 2, ig = tid & 3;
    short8 o0, o1;
#pragma unroll
    for (int m = 0; m < 8; m++) {
        o0[m] = (short)f2bf(tile[ig * 16 + m][jl]);
        o1[m] = (short)f2bf(tile[ig * 16 + 8 + m][jl]);
    }
    u16* dst = out + (long)b * IJ + (long)(j0 + jl) * 256 + i0 + ig * 16;
    *(short8*)dst = o0;
    *(short8*)(dst + 8) = o1;
}

// ---------------------------------------------------------------------------
// Causal flash attention, S^T formulation (R0 structure, frozen) +
// T13 defer-max: skip the O-rescale (8 shfls + 32 mults + 2 exp2) when
// __all(max growth <= 8). All P since the last rescale share one max
// reference (standard stale-max flash); P <= 2^8, bf16 truncation error
// is relative so accuracy is unchanged. First iter auto-rescales
// (mrow = -3e38 -> growth = +inf).
// ---------------------------------------------------------------------------
__global__ __launch_bounds__(256, 2) void flash_attn(
    const u16* __restrict__ Qg, const u16* __restrict__ Kg,
    const u16* __restrict__ Vt, u16* __restrict__ Og)
{
    __shared__ __align__(16) u16 plds[4][32 * 72];   // per-wave P, stride 72 u16
    const int tid = threadIdx.x;
    const int wv = tid >> 6, lane = tid & 63;
    const int quad = lane >> 4, l15 = lane & 15;
    const int p = blockIdx.x;                    // physical block 0..511
    const int bidx = (p & 7) * 64 + (p >> 3);    // XCD-contiguous logical block
    const int gw = bidx * 4 + wv;
    const int pr = gw & 15;
    const int bh = gw >> 4;                  // 0..127, same for all waves in block
    const int hh = bh & 15, bb = bh >> 4;
    const long SD = 1024L * 1024L;
    const u16* Qb = Qg + (long)bb * SD + hh * 64;
    const u16* Kb = Kg + (long)bb * SD + hh * 64;
    const u16* Vb = Vt + (long)bb * SD + (long)hh * 64 * 1024;
    u16* myp = plds[wv];

    for (int half = 0; half < 2; half++) {
        const int qt = half ? (31 - pr) : pr;
        const int q0 = qt * 32;

        short8 qf[2][2];
#pragma unroll
        for (int mt = 0; mt < 2; mt++)
#pragma unroll
            for (int kb = 0; kb < 2; kb++)
                qf[mt][kb] = *(const short8*)(Qb + (long)(q0 + mt * 16 + l15) * 1024 + kb * 32 + quad * 8);

        f32x4 o[2][4];
        float mrow[2] = {-3e38f, -3e38f}, lrow[2] = {0.f, 0.f};
#pragma unroll
        for (int mt = 0; mt < 2; mt++)
#pragma unroll
            for (int nt = 0; nt < 4; nt++) o[mt][nt] = (f32x4){0.f, 0.f, 0.f, 0.f};

        const int ntile = (q0 + 95) >> 6;    // ceil((q0+32)/64)
        short8 kf[4][2], kn[4][2];
#pragma unroll
        for (int kt = 0; kt < 4; kt++)
#pragma unroll
            for (int kb = 0; kb < 2; kb++)
                kf[kt][kb] = *(const short8*)(Kb + (long)(kt * 16 + l15) * 1024 + kb * 32 + quad * 8);

        for (int it = 0; it < ntile; it++) {
            const int k2 = it * 64;
            const bool last = (it == ntile - 1);
            // S^T[key][q] = K·Q^T
            f32x4 st[4][2];
            __builtin_amdgcn_s_setprio(1);
#pragma unroll
            for (int kt = 0; kt < 4; kt++)
#pragma unroll
                for (int q_ = 0; q_ < 2; q_++) {
                    f32x4 z = (f32x4){0.f, 0.f, 0.f, 0.f};
                    z = __builtin_amdgcn_mfma_f32_16x16x32_bf16(kf[kt][0], qf[q_][0], z, 0, 0, 0);
                    z = __builtin_amdgcn_mfma_f32_16x16x32_bf16(kf[kt][1], qf[q_][1], z, 0, 0, 0);
                    st[kt][q_] = z;
                }
            __builtin_amdgcn_s_setprio(0);
            // V loads for this iter (latency hidden under softmax)
            short8 vf[4][2];
#pragma unroll
            for (int nt = 0; nt < 4; nt++)
#pragma unroll
                for (int kh = 0; kh < 2; kh++)
                    vf[nt][kh] = *(const short8*)(Vb + (long)(nt * 16 + l15) * 1024 + k2 + kh * 32 + quad * 8);
            // prefetch next K tile
            if (it + 1 < ntile) {
#pragma unroll
                for (int kt = 0; kt < 4; kt++)
#pragma unroll
                    for (int kb = 0; kb < 2; kb++)
                        kn[kt][kb] = *(const short8*)(Kb + (long)(k2 + 64 + kt * 16 + l15) * 1024 + kb * 32 + quad * 8);
            }
            // online softmax per q-column (lane&15 holds q): current maxes
            float cm2[2];
#pragma unroll
            for (int q_ = 0; q_ < 2; q_++) {
                if (last) {
#pragma unroll
                    for (int kt = 0; kt < 4; kt++)
#pragma unroll
                        for (int r = 0; r < 4; r++)
                            if (k2 + kt * 16 + quad * 4 + r > q0 + q_ * 16 + l15)
                                st[kt][q_][r] = -3e38f;
                }
                // balanced max tree (exact)
                float t0 = fmaxf(fmaxf(st[0][q_][0], st[0][q_][1]), fmaxf(st[0][q_][2], st[0][q_][3]));
                float t1 = fmaxf(fmaxf(st[1][q_][0], st[1][q_][1]), fmaxf(st[1][q_][2], st[1][q_][3]));
                float t2 = fmaxf(fmaxf(st[2][q_][0], st[2][q_][1]), fmaxf(st[2][q_][2], st[2][q_][3]));
                float t3 = fmaxf(fmaxf(st[3][q_][0], st[3][q_][1]), fmaxf(st[3][q_][2], st[3][q_][3]));
                float cm = fmaxf(fmaxf(t0, t1), fmaxf(t2, t3));
                cm = fmaxf(cm, __shfl_xor(cm, 16));
                cm = fmaxf(cm, __shfl_xor(cm, 32));
                cm2[q_] = cm;
            }
            // T13 defer-max: rescale only if some q-col grew by > 8
            const float grow = fmaxf(cm2[0] - mrow[0], cm2[1] - mrow[1]);
            const bool resc = !__all(grow <= 8.0f);
            float am[2] = {1.f, 1.f};
            if (resc) {
#pragma unroll
                for (int q_ = 0; q_ < 2; q_++) {
                    const float mn = fmaxf(mrow[q_], cm2[q_]);
                    am[q_] = exp2f(mrow[q_] - mn);
                    mrow[q_] = mn;
                }
            }
#pragma unroll
            for (int q_ = 0; q_ < 2; q_++) {
                // fold +log2(1+2^-9) so the truncating bf16 pack is ~unbiased
                const float moff = 0.00281502f - mrow[q_];
                float s4[4];
#pragma unroll
                for (int kt = 0; kt < 4; kt++) {
                    float p0 = exp2f(st[kt][q_][0] + moff);
                    float p1 = exp2f(st[kt][q_][1] + moff);
                    float p2 = exp2f(st[kt][q_][2] + moff);
                    float p3 = exp2f(st[kt][q_][3] + moff);
                    s4[kt] = (p0 + p1) + (p2 + p3);
                    u32 w0 = pack_bf(p0, p1);
                    u32 w1 = pack_bf(p2, p3);
                    *(uint2*)&myp[(q_ * 16 + l15) * 72 + kt * 16 + quad * 4] = make_uint2(w0, w1);
                }
                float rs = (s4[0] + s4[1]) + (s4[2] + s4[3]);
                rs += __shfl_xor(rs, 16);
                rs += __shfl_xor(rs, 32);
                lrow[q_] = lrow[q_] * am[q_] + rs;
            }
            // redistribute alpha + rescale O only when a rescale happened
            if (resc) {
                float av[2][4];
#pragma unroll
                for (int mt = 0; mt < 2; mt++)
#pragma unroll
                    for (int r = 0; r < 4; r++)
                        av[mt][r] = __shfl(am[mt], quad * 4 + r);
#pragma unroll
                for (int mt = 0; mt < 2; mt++)
#pragma unroll
                    for (int nt = 0; nt < 4; nt++)
#pragma unroll
                        for (int r = 0; r < 4; r++) o[mt][nt][r] *= av[mt][r];
            }
            asm volatile("s_waitcnt lgkmcnt(0)" ::: "memory");
            short8 pf0[2], pf1[2];
#pragma unroll
            for (int kh = 0; kh < 2; kh++) {
                pf0[kh] = *(const short8*)&myp[(l15) * 72 + kh * 32 + quad * 8];
                pf1[kh] = *(const short8*)&myp[(16 + l15) * 72 + kh * 32 + quad * 8];
            }
            __builtin_amdgcn_s_setprio(1);
#pragma unroll
            for (int nt = 0; nt < 4; nt++)
#pragma unroll
                for (int kh = 0; kh < 2; kh++) {
                    o[0][nt] = __builtin_amdgcn_mfma_f32_16x16x32_bf16(pf0[kh], vf[nt][kh], o[0][nt], 0, 0, 0);
                    o[1][nt] = __builtin_amdgcn_mfma_f32_16x16x32_bf16(pf1[kh], vf[nt][kh], o[1][nt], 0, 0, 0);
                }
            __builtin_amdgcn_s_setprio(0);
            if (it + 1 < ntile) {
#pragma unroll
                for (int kt = 0; kt < 4; kt++)
#pragma unroll
                    for (int kb = 0; kb < 2; kb++) kf[kt][kb] = kn[kt][kb];
            }
        }
        // epilogue
#pragma unroll
        for (int mt = 0; mt < 2; mt++)
#pragma unroll
            for (int r = 0; r < 4; r++) {
                const float li = 1.0f / __shfl(lrow[mt], quad * 4 + r);
                const long row = q0 + mt * 16 + quad * 4 + r;
#pragma unroll
                for (int nt = 0; nt < 4; nt++)
                    Og[(long)bb * SD + row * 1024 + hh * 64 + nt * 16 + l15] =
                        f2bf(o[mt][nt][r] * li);
            }
    }
}

// ---------------------------------------------------------------------------
extern "C" void kernel_launch(void* const* d_in, const int* in_sizes, int n_in,
                              void* d_out, int out_size, void* d_ws, size_t ws_size,
                              hipStream_t stream)
{
    const float* x   = (const float*)d_in[0];
    const float* imp = (const float*)d_in[1];
    const float* cn  = (const float*)d_in[6];
    const float* ep  = (const float*)d_in[7];
    const float* Wo  = (const float*)d_in[8];
    float* outp = (float*)d_out;
    char* ws = (char*)d_ws;

    // d_out (33.55 MB) doubles as scratch for x_hi/x_lo until the final GEMM.
    u16* xh = (u16*)d_out;                    // [8192][1024] bf16
    u16* xl = xh + 8388608;                   // [8192][1024] bf16

    u16*   Wh     = (u16*)(ws + 0);           // [256][1024] bf16
    u16*   Wl     = (u16*)(ws + 524288);      // [256][1024] bf16
    u16*   Wobf   = (u16*)(ws + 1048576);     // [1024][1024] bf16
    float* w_raw  = (float*)(ws + 3145728);   // [4][8][64]
    float* topw   = (float*)(ws + 3153920);   // [4][8][16]
    int*   topi   = (int*)(ws + 3155968);     // [4][8][16]
    // logits seg buffers: L0 in the pre-Kb region; L1/L2 park in the Qb
    // region (both dead before gemm_qkv writes Qb).
    float* logit0 = (float*)(ws + 4194304);   // [8192][256] fp32
    float* logit1 = (float*)(ws + 33554432);  // [8192][256] fp32 (Qb region)
    float* logit2 = (float*)(ws + 41943040);  // [8192][256] fp32 (Qb region)
    u16*   scT    = (u16*)(ws + 12582912);    // [8][256][1024] (dead after h GEMM)
    u16*   eQT    = (u16*)(ws + 16777216);    // [8][1024][256] (dead after QKV GEMM)
    u16*   Kb     = (u16*)(ws + 4194304);     // [8][1024][1024] (written after logits die)
    u16*   hbuf   = (u16*)(ws + 20971520);    // [8][1024][256]
    u16*   eKT    = (u16*)(ws + 25165824);    // [8][1024][256]
    u16*   eVT    = (u16*)(ws + 29360128);    // [8][1024][256]
    u16*   Qb     = (u16*)(ws + 33554432);    // [8][1024][1024]
    u16*   VTb    = (u16*)(ws + 50331648);    // [8][1024(D)][1024(S)]
    u16*   aout   = (u16*)(ws + 67108864);    // [8][1024][1024]

    // 0) precision splits / conversions
    cvt_split<<<dim3(8192), 256, 0, stream>>>(x, xh, xl, 2097152);
    cvt_split_w4<<<dim3(256), 256, 0, stream>>>(
        (const float*)d_in[2], (const float*)d_in[3],
        (const float*)d_in[4], (const float*)d_in[5], Wh, Wl);
    cvt_bf<<<dim3(1024), 256, 0, stream>>>(Wo, Wobf, 262144);
    hipMemsetAsync(w_raw, 0, 4 * 8 * 64 * 4, stream);

    // 1) router logits, split-bf16, one segment per z (384 blocks, BK=128)
    gemm_router<<<dim3(64, 2, 3), 256, 0, stream>>>(
        xh, xl, Wh, Wl, logit0, logit1, logit2);
    // 2) softmax + importance aggregation, 3) top-k (all fp32)
    router_agg<<<dim3(256), 128, 0, stream>>>(logit0, logit1, logit2, imp, w_raw);
    topk_kernel<<<dim3(32), 64, 0, stream>>>(w_raw, topw, topi);
    // 4) gathered expert mixes (fp32 pools -> bf16, stored transposed/K-contig)
    gather_mix<<<dim3(16, 4, 8), 256, 0, stream>>>(cn, topw + 0 * 128, topi + 0 * 128, scT, 1024, 256, 16);
    gather_mix3<<<dim3(4, 16, 24), 256, 0, stream>>>(ep, topw, topi, eQT, eKT, eVT);
    // 5) h[b] = x[b] @ scT[b]^T   (M=1024,N=256,K=1024, BK=128; 128 blocks)
    gemm_bt<u16, 128><<<dim3(8, 2, 8), 256, 0, stream>>>(
        xh, 1024, 1048576, scT, 1024, 262144, hbuf, 256, 262144, 1024, 1.0f);
    // 6) Q/K/V^T in one launch (1536 blocks, BK=64 -> 4 K-steps)
    gemm_qkv<<<dim3(8, 8, 24), 256, 0, stream>>>(hbuf, eQT, eKT, eVT, Qb, Kb, VTb);
    // 7) causal flash attention (512 blocks, XCD-grouped, defer-max)
    flash_attn<<<dim3(512), 256, 0, stream>>>(Qb, Kb, VTb, aout);
    // 8) output projection: out = aout @ W_O^T (fp32 out, BK=128; 512 blocks
    //    = 2/CU, 128KB LDS total still fits -> no occupancy loss)
    gemm_bt<float, 128><<<dim3(64, 8, 1), 256, 0, stream>>>(
        aout, 1024, 0, Wobf, 1024, 0, outp, 1024, 0, 1024, 1.0f);
}